// Round 16
// baseline (1670.174 us; speedup 1.0000x reference)
//
#include <hip/hip_runtime.h>
#include <cstdint>
#include <cstddef>

#define B_ 8
#define N_ 4096
#define K_ 20
#define MT1 1024
#define KN2_ROWS 64
#define KN2_TILE 128

// separately-rounded multiply-add (numpy einsum-noopt style: no FMA contraction)
__device__ __forceinline__ float madd(float a, float b, float acc) {
  return __fadd_rn(acc, __fmul_rn(a, b));
}

__device__ __forceinline__ float xx3f(float a, float b, float c) {
  return __fadd_rn(__fadd_rn(__fmul_rn(a, a), __fmul_rn(b, b)), __fmul_rn(c, c));
}

// broadcast lane value via v_readlane (VALU pipe, no LDS traffic)
__device__ __forceinline__ float rlane(float v, int l) {
  return __int_as_float(__builtin_amdgcn_readlane(__float_as_int(v), l));
}

// ---------- parallel predicated insert (r10-proven: stays in registers) ----------
// pre: list sorted desc; equal keys keep arrival (index-asc) order. No-op if pr <= kp[19].
__device__ __forceinline__ void ins20(float (&kp)[K_], int (&ki)[K_], float pr, int m) {
  bool c[K_];
#pragma unroll
  for (int t = 0; t < K_; ++t) c[t] = (pr > kp[t]);
#pragma unroll
  for (int t = K_ - 1; t >= 1; --t) {
    kp[t] = c[t] ? (c[t - 1] ? kp[t - 1] : pr) : kp[t];
    ki[t] = c[t] ? (c[t - 1] ? ki[t - 1] : m) : ki[t];
  }
  kp[0] = c[0] ? pr : kp[0];
  ki[0] = c[0] ? m  : ki[0];
}

// ---------- stage 1 KNN: wave-per-row collective top-k (lane = sorted slot) ----------
__global__ __launch_bounds__(256, 4) void knn1_kernel(const float* __restrict__ x, int* __restrict__ idxo) {
  __shared__ float4 tile[MT1];    // 16 KiB: 1024 cands (x,y,z,xx)
  int bid = blockIdx.x;
  int b = bid / (N_ / 4);
  int r0 = (bid % (N_ / 4)) * 4;
  int tid = threadIdx.x;
  int wv = tid >> 6, lane = tid & 63;
  int row = r0 + wv;
  const float* xb = x + (size_t)b * 3 * N_;
  float ox = xb[row], oy = xb[N_ + row], oz = xb[2 * N_ + row];
  float nxxn = -xx3f(ox, oy, oz);
  float kv = -3.0e38f;
  int kidx = 0x7fffffff;
  for (int t0 = 0; t0 < N_; t0 += MT1) {
    __syncthreads();
    for (int l = tid; l < MT1; l += 256) {
      float4 p;
      p.x = xb[t0 + l]; p.y = xb[N_ + t0 + l]; p.z = xb[2 * N_ + t0 + l];
      p.w = xx3f(p.x, p.y, p.z);
      tile[l] = p;
    }
    __syncthreads();
    for (int s = 0; s < MT1; s += 64) {
      float4 p = tile[s + lane];
      float d = __fmul_rn(ox, p.x);
      d = madd(oy, p.y, d);
      d = madd(oz, p.z, d);
      float pr = __fsub_rn(__fadd_rn(nxxn, __fadd_rn(d, d)), p.w);
      float thr = __shfl(kv, 19);
      unsigned long long mask = __ballot(pr > thr);
      int mbase = t0 + s;
      while (mask) {
        int l = __ffsll(mask) - 1;
        mask &= mask - 1;
        float val = __shfl(pr, l);
        int midx = mbase + l;
        bool c = (val > kv);
        float upv = __shfl_up(kv, 1);
        int upi = __shfl_up(kidx, 1);
        int upc = __shfl_up((int)c, 1);
        bool pc = (lane == 0) ? false : (upc != 0);
        kv = c ? (pc ? upv : val) : kv;
        kidx = c ? (pc ? upi : midx) : kidx;
      }
    }
  }
  if (lane < K_) idxo[((size_t)b * N_ + row) * K_ + lane] = kidx;
}

// ---------- stage 2 KNN: lane=row; 4-cands-per-ds_read + readlane broadcast ----------
__global__ __launch_bounds__(256, 2) void knn2_kernel(const float* __restrict__ x1f,
                                                      const float* __restrict__ xxf,
                                                      int* __restrict__ idxo) {
  __shared__ __align__(16) unsigned char smem[33280];
  float* tile = (float*)smem;                 // 128 cands x 64 floats = 32768 B
  float* txx  = tile + KN2_TILE * 64;         // 128 floats
  float* mD = (float*)smem;                   // merge alias: 4*64*20 floats
  unsigned short* mI = (unsigned short*)(smem + 20480);
  int bid = blockIdx.x;
  int b = bid >> 6;
  int r0 = (bid & 63) * KN2_ROWS;
  int tid = threadIdx.x;
  int lane = tid & 63, wv = tid >> 6;
  int row = r0 + lane;
  const float* xrow = x1f + ((size_t)b * N_ + row) * 64;
  float own[64];
#pragma unroll
  for (int c4 = 0; c4 < 16; ++c4) {
    float4 t = ((const float4*)xrow)[c4];
    own[c4 * 4 + 0] = t.x; own[c4 * 4 + 1] = t.y;
    own[c4 * 4 + 2] = t.z; own[c4 * 4 + 3] = t.w;
  }
  float nxxn = -xxf[(size_t)b * N_ + row];
  float kp[K_]; int ki[K_];
#pragma unroll
  for (int t = 0; t < K_; ++t) { kp[t] = -3.0e38f; ki[t] = 65535; }
  int csub = lane >> 4;          // which of 4 grouped candidates this lane loads
  int chunk = lane & 15;         // which float4 chunk
  for (int t0 = 0; t0 < N_; t0 += KN2_TILE) {
    __syncthreads();
    for (int l = tid; l < KN2_TILE * 16; l += 256) {
      int ml = l >> 4, c4 = l & 15;
      ((float4*)tile)[ml * 16 + c4] =
          ((const float4*)(x1f + ((size_t)b * N_ + t0 + ml) * 64))[c4];
    }
    for (int l = tid; l < KN2_TILE; l += 256) txx[l] = xxf[(size_t)b * N_ + t0 + l];
    __syncthreads();
    // wave wv owns candidates mi = wv + 4q, q = 0..31; grouped 4 per vector load
    for (int qb = 0; qb < 32; qb += 4) {
      int mi_l = wv + 4 * (qb + csub);
      float4 creg = *(const float4*)&tile[mi_l * 64 + (chunk << 2)];
      float d0 = 0.f, d1 = 0.f, d2 = 0.f, d3 = 0.f;
#pragma unroll
      for (int k = 0; k < 16; ++k) {
        float o0 = own[4 * k + 0], o1 = own[4 * k + 1];
        float o2 = own[4 * k + 2], o3 = own[4 * k + 3];
        d0 = madd(o0, rlane(creg.x, k), d0);
        d1 = madd(o0, rlane(creg.x, 16 + k), d1);
        d2 = madd(o0, rlane(creg.x, 32 + k), d2);
        d3 = madd(o0, rlane(creg.x, 48 + k), d3);
        d0 = madd(o1, rlane(creg.y, k), d0);
        d1 = madd(o1, rlane(creg.y, 16 + k), d1);
        d2 = madd(o1, rlane(creg.y, 32 + k), d2);
        d3 = madd(o1, rlane(creg.y, 48 + k), d3);
        d0 = madd(o2, rlane(creg.z, k), d0);
        d1 = madd(o2, rlane(creg.z, 16 + k), d1);
        d2 = madd(o2, rlane(creg.z, 32 + k), d2);
        d3 = madd(o2, rlane(creg.z, 48 + k), d3);
        d0 = madd(o3, rlane(creg.w, k), d0);
        d1 = madd(o3, rlane(creg.w, 16 + k), d1);
        d2 = madd(o3, rlane(creg.w, 32 + k), d2);
        d3 = madd(o3, rlane(creg.w, 48 + k), d3);
      }
      int mi0 = wv + 4 * qb;
      float pr0 = __fsub_rn(__fadd_rn(nxxn, __fadd_rn(d0, d0)), txx[mi0]);
      float pr1 = __fsub_rn(__fadd_rn(nxxn, __fadd_rn(d1, d1)), txx[mi0 + 4]);
      float pr2 = __fsub_rn(__fadd_rn(nxxn, __fadd_rn(d2, d2)), txx[mi0 + 8]);
      float pr3 = __fsub_rn(__fadd_rn(nxxn, __fadd_rn(d3, d3)), txx[mi0 + 12]);
      if (pr0 > kp[K_ - 1]) ins20(kp, ki, pr0, t0 + mi0);
      if (pr1 > kp[K_ - 1]) ins20(kp, ki, pr1, t0 + mi0 + 4);
      if (pr2 > kp[K_ - 1]) ins20(kp, ki, pr2, t0 + mi0 + 8);
      if (pr3 > kp[K_ - 1]) ins20(kp, ki, pr3, t0 + mi0 + 12);
    }
  }
  __syncthreads();   // tile dead; alias merge arrays
  int li = wv * 64 + lane;
#pragma unroll
  for (int t = 0; t < K_; ++t) { mD[li * K_ + t] = kp[t]; mI[li * K_ + t] = (unsigned short)ki[t]; }
  __syncthreads();
  if (tid < 64) {
    int h[4] = {0, 0, 0, 0};
    int* op = idxo + ((size_t)b * N_ + r0 + tid) * K_;
    for (int j = 0; j < K_; ++j) {
      float best = -3.39e38f; int bi = 0x7fffffff; int bs = 0;
#pragma unroll
      for (int s = 0; s < 4; ++s) {
        int hs = h[s];
        float dv = (hs < K_) ? mD[(s * 64 + tid) * K_ + hs] : -3.4e38f;
        int   iv = (hs < K_) ? (int)mI[(s * 64 + tid) * K_ + hs] : 0x7fffffff;
        if (dv > best || (dv == best && iv < bi)) { best = dv; bi = iv; bs = s; }
      }
      op[j] = bi;
#pragma unroll
      for (int s = 0; s < 4; ++s) h[s] += (s == bs) ? 1 : 0;
    }
  }
}

// ---------- exact stage-1 value path (numpy-bit-exact; feeds knn2) ----------
__device__ __forceinline__ float chain6(float w0, float w1, float w2, float w3, float w4, float w5,
                                        const float* fp) {
  float acc = __fmul_rn(w0, fp[0]);
  acc = madd(w1, fp[1], acc);
  acc = madd(w2, fp[2], acc);
  acc = madd(w3, fp[3], acc);
  acc = madd(w4, fp[4], acc);
  acc = madd(w5, fp[5], acc);
  return acc;
}

__device__ __forceinline__ float leaf_combine(const float (&r8)[8]) {
  return __fadd_rn(__fadd_rn(__fadd_rn(r8[0], r8[1]), __fadd_rn(r8[2], r8[3])),
                   __fadd_rn(__fadd_rn(r8[4], r8[5]), __fadd_rn(r8[6], r8[7])));
}

template <int VAR>
__global__ __launch_bounds__(256) void leaf1_kernel(const float* __restrict__ x,
                                                    const float* __restrict__ W1,
                                                    const int* __restrict__ idx,
                                                    const float* __restrict__ pm,
                                                    float* __restrict__ leafbuf) {
  __shared__ float feat[2560];
  __shared__ int sidx[320];
  int b = blockIdx.x >> 8;
  int bg = blockIdx.x & 255;
  int n0 = bg * 16;
  int tid = threadIdx.x;
  const float* xb = x + (size_t)b * 3 * N_;
  for (int q = tid; q < 320; q += 256) sidx[q] = idx[((size_t)b * N_ + n0) * K_ + q];
  __syncthreads();
  for (int q = tid; q < 2560; q += 256) {
    int f = q >> 3, c = q & 7;
    int n = n0 + f / 20;
    float v = 0.f;
    if (c < 3) {
      int m = sidx[f];
      v = __fsub_rn(xb[c * N_ + m], xb[c * N_ + n]);
    } else if (c < 6) {
      v = xb[(c - 3) * N_ + n];
    }
    feat[q] = v;
  }
  __syncthreads();
  int o = tid & 63, lg = tid >> 6;
  float w0 = W1[o * 6 + 0], w1 = W1[o * 6 + 1], w2 = W1[o * 6 + 2];
  float w3 = W1[o * 6 + 3], w4 = W1[o * 6 + 4], w5 = W1[o * 6 + 5];
  float mu = VAR ? pm[o] : 0.f;
  const float* fb = feat + lg * 640;
  float r8[8];
#pragma unroll
  for (int jj = 0; jj < 8; ++jj) {
    float y = chain6(w0, w1, w2, w3, w4, w5, fb + jj * 8);
    if (VAR) { float t = __fsub_rn(y, mu); y = __fmul_rn(t, t); }
    r8[jj] = y;
  }
  for (int i = 1; i < 10; ++i) {
#pragma unroll
    for (int jj = 0; jj < 8; ++jj) {
      float y = chain6(w0, w1, w2, w3, w4, w5, fb + (i * 8 + jj) * 8);
      if (VAR) { float t = __fsub_rn(y, mu); y = __fmul_rn(t, t); }
      r8[jj] = __fadd_rn(r8[jj], y);
    }
  }
  int l = bg * 4 + lg;
  leafbuf[((size_t)b * 1024 + l) * 64 + o] = leaf_combine(r8);
}

template <int MODE>
__global__ __launch_bounds__(512) void tree_kernel(const float* __restrict__ lb,
                                                   float* __restrict__ pm) {
  __shared__ float red[512];
  int t = threadIdx.x;
  int b = t >> 6, o = t & 63;
  const float* base = lb + (size_t)b * 1024 * 64 + o;
  float part[32];
#pragma unroll
  for (int p = 0; p < 32; ++p) {
    float a[32];
#pragma unroll
    for (int q = 0; q < 32; ++q) a[q] = base[(size_t)(p * 32 + q) * 64];
#pragma unroll
    for (int lev = 16; lev >= 1; lev >>= 1) {
#pragma unroll
      for (int q = 0; q < 16; ++q) {
        if (q < lev) a[q] = __fadd_rn(a[2 * q], a[2 * q + 1]);
      }
    }
    part[p] = a[0];
  }
#pragma unroll
  for (int lev = 16; lev >= 1; lev >>= 1) {
#pragma unroll
    for (int q = 0; q < 16; ++q) {
      if (q < lev) part[q] = __fadd_rn(part[2 * q], part[2 * q + 1]);
    }
  }
  red[t] = part[0];
  __syncthreads();
  if (t < 64) {
    float acc = red[t];
#pragma unroll
    for (int bb = 1; bb < 8; ++bb) acc = __fadd_rn(acc, red[bb * 64 + t]);
    float mv = __fdiv_rn(acc, 655360.0f);
    if (MODE == 0) pm[t] = mv;
    else pm[64 + t] = __fdiv_rn(1.0f, __fsqrt_rn(__fadd_rn(mv, 1e-5f)));
  }
}

__global__ __launch_bounds__(256) void final1_kernel(const float* __restrict__ x,
                                                     const float* __restrict__ W1,
                                                     const int* __restrict__ idx,
                                                     const float* __restrict__ pm,
                                                     const float* __restrict__ g,
                                                     const float* __restrict__ be,
                                                     float* __restrict__ x1f,
                                                     float* __restrict__ xxf) {
  __shared__ float feat[640];
  __shared__ int sidx[80];
  __shared__ float xrow[4][64];
  int b = blockIdx.x >> 10;
  int rg = blockIdx.x & 1023;
  int n0 = rg * 4;
  int tid = threadIdx.x;
  const float* xb = x + (size_t)b * 3 * N_;
  for (int q = tid; q < 80; q += 256) sidx[q] = idx[((size_t)b * N_ + n0) * K_ + q];
  __syncthreads();
  for (int q = tid; q < 640; q += 256) {
    int f = q >> 3, c = q & 7;
    int n = n0 + f / 20;
    float v = 0.f;
    if (c < 3) {
      int m = sidx[f];
      v = __fsub_rn(xb[c * N_ + m], xb[c * N_ + n]);
    } else if (c < 6) {
      v = xb[(c - 3) * N_ + n];
    }
    feat[q] = v;
  }
  __syncthreads();
  int o = tid & 63, lr = tid >> 6;
  float w0 = W1[o * 6 + 0], w1 = W1[o * 6 + 1], w2 = W1[o * 6 + 2];
  float w3 = W1[o * 6 + 3], w4 = W1[o * 6 + 4], w5 = W1[o * 6 + 5];
  float mu = pm[o], rs = pm[64 + o], gg = g[o], bb = be[o];
  float mx = 0.f;
  for (int j = 0; j < 20; ++j) {
    float y = chain6(w0, w1, w2, w3, w4, w5, feat + (lr * 20 + j) * 8);
    float tt = __fsub_rn(y, mu);
    float yn = __fmul_rn(tt, rs);
    float yg = __fmul_rn(yn, gg);
    float yb = __fadd_rn(yg, bb);
    float val = (yb >= 0.f) ? yb : __fmul_rn(0.2f, yb);
    mx = (j == 0) ? val : fmaxf(mx, val);
  }
  int n = n0 + lr;
  x1f[((size_t)b * N_ + n) * 64 + o] = mx;
  xrow[lr][o] = mx;
  __syncthreads();
  if (tid < 4) {
    float acc = __fmul_rn(xrow[tid][0], xrow[tid][0]);
#pragma unroll
    for (int oo = 1; oo < 64; ++oo) acc = __fadd_rn(acc, __fmul_rn(xrow[tid][oo], xrow[tid][oo]));
    xxf[(size_t)b * N_ + n0 + tid] = acc;
  }
}

// ---------- fast stage-2 value path (post-KNN: continuous, fast math OK) ----------
__global__ __launch_bounds__(256) void proj2f_kernel(const float* __restrict__ x1f,
                                                     const float* __restrict__ W2,
                                                     float* __restrict__ u, float* __restrict__ v) {
  __shared__ float w[64 * 128];
  int tid = threadIdx.x;
  for (int l = tid; l < 64 * 128; l += 256) w[l] = W2[l];
  __syncthreads();
  int i = blockIdx.x * 256 + tid;
  const float* xr = x1f + (size_t)i * 64;
  float4 xv[16];
#pragma unroll
  for (int c4 = 0; c4 < 16; ++c4) xv[c4] = ((const float4*)xr)[c4];
  float* up = u + (size_t)i * 64;
  float* vp = v + (size_t)i * 64;
#pragma unroll
  for (int og = 0; og < 16; ++og) {
    float ur[4], vr[4];
#pragma unroll
    for (int k = 0; k < 4; ++k) {
      int o = og * 4 + k;
      const float* wr = &w[o * 128];
      float ua = 0.f, ub = 0.f, ta = 0.f, tb = 0.f;
#pragma unroll
      for (int c4 = 0; c4 < 16; c4 += 2) {
        float4 wa0 = *(const float4*)&wr[c4 * 4];
        float4 wa1 = *(const float4*)&wr[c4 * 4 + 4];
        float4 wb0 = *(const float4*)&wr[64 + c4 * 4];
        float4 wb1 = *(const float4*)&wr[64 + c4 * 4 + 4];
        float4 x0 = xv[c4], x1q = xv[c4 + 1];
        ua = fmaf(wa0.x, x0.x, ua); ua = fmaf(wa0.y, x0.y, ua);
        ua = fmaf(wa0.z, x0.z, ua); ua = fmaf(wa0.w, x0.w, ua);
        ub = fmaf(wa1.x, x1q.x, ub); ub = fmaf(wa1.y, x1q.y, ub);
        ub = fmaf(wa1.z, x1q.z, ub); ub = fmaf(wa1.w, x1q.w, ub);
        ta = fmaf(wb0.x, x0.x, ta); ta = fmaf(wb0.y, x0.y, ta);
        ta = fmaf(wb0.z, x0.z, ta); ta = fmaf(wb0.w, x0.w, ta);
        tb = fmaf(wb1.x, x1q.x, tb); tb = fmaf(wb1.y, x1q.y, tb);
        tb = fmaf(wb1.z, x1q.z, tb); tb = fmaf(wb1.w, x1q.w, tb);
      }
      float uu = ua + ub, tt = ta + tb;
      ur[k] = uu; vr[k] = tt - uu;
    }
    ((float4*)up)[og] = make_float4(ur[0], ur[1], ur[2], ur[3]);
    ((float4*)vp)[og] = make_float4(vr[0], vr[1], vr[2], vr[3]);
  }
}

__global__ __launch_bounds__(256) void gatherf_kernel(const float* __restrict__ u,
                                                      const float* __restrict__ v,
                                                      const int* __restrict__ idx,
                                                      float* __restrict__ ymax,
                                                      float* __restrict__ ymin,
                                                      float* __restrict__ partbuf) {
  __shared__ float sred[4][128];
  int tid = threadIdx.x;
  int g = blockIdx.x * 32;
  int nl = tid >> 3, oc = tid & 7;
  int i = g + nl;
  int o0 = oc * 8;
  const float* vp = v + (size_t)i * 64 + o0;
  float vv[8];
  *(float4*)&vv[0] = *(const float4*)vp;
  *(float4*)&vv[4] = *(const float4*)(vp + 4);
  float s[8], q[8], mx[8], mn[8];
#pragma unroll
  for (int t = 0; t < 8; ++t) { s[t] = 0.f; q[t] = 0.f; mx[t] = -3.0e38f; mn[t] = 3.0e38f; }
  const int* ip = idx + (size_t)i * K_;
  int bbase = (i >> 12) << 12;
  for (int j = 0; j < K_; ++j) {
    int m = ip[j];
    const float* upp = u + ((size_t)(bbase + m)) * 64 + o0;
    float yv[8];
    *(float4*)&yv[0] = *(const float4*)upp;
    *(float4*)&yv[4] = *(const float4*)(upp + 4);
#pragma unroll
    for (int t = 0; t < 8; ++t) {
      float y = yv[t] + vv[t];
      s[t] += y; q[t] = fmaf(y, y, q[t]);
      mx[t] = fmaxf(mx[t], y); mn[t] = fminf(mn[t], y);
    }
  }
  float* mxp = ymax + (size_t)i * 64 + o0;
  float* mnp = ymin + (size_t)i * 64 + o0;
  *(float4*)mxp = make_float4(mx[0], mx[1], mx[2], mx[3]);
  *(float4*)(mxp + 4) = make_float4(mx[4], mx[5], mx[6], mx[7]);
  *(float4*)mnp = make_float4(mn[0], mn[1], mn[2], mn[3]);
  *(float4*)(mnp + 4) = make_float4(mn[4], mn[5], mn[6], mn[7]);
  int wv = tid >> 6;
#pragma unroll
  for (int t = 0; t < 8; ++t) {
    float sv = s[t], qv = q[t];
    sv += __shfl_xor(sv, 8);  qv += __shfl_xor(qv, 8);
    sv += __shfl_xor(sv, 16); qv += __shfl_xor(qv, 16);
    sv += __shfl_xor(sv, 32); qv += __shfl_xor(qv, 32);
    if ((tid & 63) < 8) { sred[wv][o0 + t] = sv; sred[wv][64 + o0 + t] = qv; }
  }
  __syncthreads();
  if (tid < 128) {
    float tot = (sred[0][tid] + sred[1][tid]) + (sred[2][tid] + sred[3][tid]);
    partbuf[(size_t)blockIdx.x * 128 + tid] = tot;
  }
}

__global__ void statred_kernel(const float* __restrict__ partbuf, double* __restrict__ stats) {
  int t = threadIdx.x;   // 128
  double acc = 0.0;
  for (int p = 0; p < 1024; ++p) acc += (double)partbuf[(size_t)p * 128 + t];
  stats[t] = acc;
}

__global__ void bnfin_kernel(const double* __restrict__ stats, const float* __restrict__ g,
                             const float* __restrict__ be, float* __restrict__ ss) {
  int o = threadIdx.x;
  if (o < 64) {
    const double cnt = (double)((size_t)B_ * N_ * K_);
    double mean = stats[o] / cnt;
    double var = stats[64 + o] / cnt - mean * mean;
    if (var < 0.0) var = 0.0;
    double sc = (double)g[o] / sqrt(var + 1e-5);
    ss[o] = (float)sc;
    ss[64 + o] = (float)((double)be[o] - mean * sc);
  }
}

__global__ __launch_bounds__(256) void final2f_kernel(const float* __restrict__ ymax,
                                                      const float* __restrict__ ymin,
                                                      const float* __restrict__ ss,
                                                      float* __restrict__ out) {
  __shared__ float ssh[128];
  __shared__ float vals[4][64];
  int tid = threadIdx.x;
  if (tid < 128) ssh[tid] = ss[tid];
  __syncthreads();
  int b = blockIdx.x >> 10;
  int l = blockIdx.x & 1023;
  int t = tid & 63, r = tid >> 6;
  size_t i = (size_t)b * N_ + l * 4 + r;
  float sc = ssh[t], sh = ssh[64 + t];
  float Y = (sc >= 0.f) ? ymax[i * 64 + t] : ymin[i * 64 + t];
  float val = fmaf(sc, Y, sh);
  val = (val >= 0.f) ? val : 0.2f * val;
  vals[r][t] = val;
  __syncthreads();
  if (tid < 64) {
    float4 o4 = make_float4(vals[0][tid], vals[1][tid], vals[2][tid], vals[3][tid]);
    *(float4*)&out[(size_t)b * 64 * N_ + (size_t)tid * N_ + l * 4] = o4;
  }
}

extern "C" void kernel_launch(void* const* d_in, const int* in_sizes, int n_in,
                              void* d_out, int out_size, void* d_ws, size_t ws_size,
                              hipStream_t stream) {
  const float* x  = (const float*)d_in[0];
  const float* W1 = (const float*)d_in[1];
  const float* g1 = (const float*)d_in[2];
  const float* b1 = (const float*)d_in[3];
  const float* W2 = (const float*)d_in[4];
  const float* g2 = (const float*)d_in[5];
  const float* b2 = (const float*)d_in[6];
  float* out = (float*)d_out;
  const size_t PN = (size_t)B_ * N_;

  int*    idx     = (int*)d_ws;
  float*  x1f     = (float*)(idx + PN * K_);
  float*  xxf     = x1f + PN * 64;
  float*  leafbuf = xxf + PN;
  float*  pm1     = leafbuf + (size_t)B_ * 1024 * 64;
  float*  uf      = pm1 + 128;
  float*  vf      = uf + PN * 64;
  float*  ymaxf   = vf + PN * 64;
  float*  yminf   = ymaxf + PN * 64;
  float*  partbuf = yminf + PN * 64;
  double* stats2  = (double*)(partbuf + 1024 * 128);
  float*  ss2     = (float*)(stats2 + 128);

  size_t need = (PN * K_ + PN * 64 * 5 + PN + (size_t)B_ * 1024 * 64 + 128 + 1024 * 128 + 128) * 4
              + 128 * 8;
  if (ws_size < need) return;

  const int knn1_grid = B_ * (N_ / 4);          // 8192 (wave-per-row)
  const int knn2_grid = B_ * (N_ / KN2_ROWS);   // 512

  // ---- stage 1 (numpy-bit-exact; feeds knn2) ----
  knn1_kernel<<<knn1_grid, 256, 0, stream>>>(x, idx);
  leaf1_kernel<0><<<B_ * 256, 256, 0, stream>>>(x, W1, idx, pm1, leafbuf);
  tree_kernel<0><<<1, 512, 0, stream>>>(leafbuf, pm1);
  leaf1_kernel<1><<<B_ * 256, 256, 0, stream>>>(x, W1, idx, pm1, leafbuf);
  tree_kernel<1><<<1, 512, 0, stream>>>(leafbuf, pm1);
  final1_kernel<<<B_ * 1024, 256, 0, stream>>>(x, W1, idx, pm1, g1, b1, x1f, xxf);

  // ---- stage 2 (knn exact; value path fast/continuous) ----
  knn2_kernel<<<knn2_grid, 256, 0, stream>>>(x1f, xxf, idx);
  proj2f_kernel<<<(int)(PN / 256), 256, 0, stream>>>(x1f, W2, uf, vf);
  gatherf_kernel<<<(int)(PN / 32), 256, 0, stream>>>(uf, vf, idx, ymaxf, yminf, partbuf);
  statred_kernel<<<1, 128, 0, stream>>>(partbuf, stats2);
  bnfin_kernel<<<1, 64, 0, stream>>>(stats2, g2, b2, ss2);
  final2f_kernel<<<B_ * 1024, 256, 0, stream>>>(ymaxf, yminf, ss2, out);
}

// Round 17
// 1581.684 us; speedup vs baseline: 1.0559x; 1.0559x over previous
//
#include <hip/hip_runtime.h>
#include <cstdint>
#include <cstddef>

#define B_ 8
#define N_ 4096
#define K_ 20
#define MT1 1024
#define KN2_TILE 128

// separately-rounded multiply-add (numpy einsum-noopt style: no FMA contraction)
__device__ __forceinline__ float madd(float a, float b, float acc) {
  return __fadd_rn(acc, __fmul_rn(a, b));
}

__device__ __forceinline__ float xx3f(float a, float b, float c) {
  return __fadd_rn(__fadd_rn(__fmul_rn(a, a), __fmul_rn(b, b)), __fmul_rn(c, c));
}

// ---------- parallel predicated insert (r10-proven: stays in registers) ----------
// pre: list sorted desc; equal keys keep arrival (index-asc) order. No-op if pr <= kp[19].
__device__ __forceinline__ void ins20(float (&kp)[K_], int (&ki)[K_], float pr, int m) {
  bool c[K_];
#pragma unroll
  for (int t = 0; t < K_; ++t) c[t] = (pr > kp[t]);
#pragma unroll
  for (int t = K_ - 1; t >= 1; --t) {
    kp[t] = c[t] ? (c[t - 1] ? kp[t - 1] : pr) : kp[t];
    ki[t] = c[t] ? (c[t - 1] ? ki[t - 1] : m) : ki[t];
  }
  kp[0] = c[0] ? pr : kp[0];
  ki[0] = c[0] ? m  : ki[0];
}

// ---------- stage 1 KNN: wave-per-row collective top-k (lane = sorted slot) ----------
__global__ __launch_bounds__(256, 4) void knn1_kernel(const float* __restrict__ x, int* __restrict__ idxo) {
  __shared__ float4 tile[MT1];    // 16 KiB: 1024 cands (x,y,z,xx)
  int bid = blockIdx.x;
  int b = bid / (N_ / 4);
  int r0 = (bid % (N_ / 4)) * 4;
  int tid = threadIdx.x;
  int wv = tid >> 6, lane = tid & 63;
  int row = r0 + wv;
  const float* xb = x + (size_t)b * 3 * N_;
  float ox = xb[row], oy = xb[N_ + row], oz = xb[2 * N_ + row];
  float nxxn = -xx3f(ox, oy, oz);
  float kv = -3.0e38f;
  int kidx = 0x7fffffff;
  for (int t0 = 0; t0 < N_; t0 += MT1) {
    __syncthreads();
    for (int l = tid; l < MT1; l += 256) {
      float4 p;
      p.x = xb[t0 + l]; p.y = xb[N_ + t0 + l]; p.z = xb[2 * N_ + t0 + l];
      p.w = xx3f(p.x, p.y, p.z);
      tile[l] = p;
    }
    __syncthreads();
    for (int s = 0; s < MT1; s += 64) {
      float4 p = tile[s + lane];
      float d = __fmul_rn(ox, p.x);
      d = madd(oy, p.y, d);
      d = madd(oz, p.z, d);
      float pr = __fsub_rn(__fadd_rn(nxxn, __fadd_rn(d, d)), p.w);
      float thr = __shfl(kv, 19);
      unsigned long long mask = __ballot(pr > thr);
      int mbase = t0 + s;
      while (mask) {
        int l = __ffsll(mask) - 1;
        mask &= mask - 1;
        float val = __shfl(pr, l);
        int midx = mbase + l;
        bool c = (val > kv);
        float upv = __shfl_up(kv, 1);
        int upi = __shfl_up(kidx, 1);
        int upc = __shfl_up((int)c, 1);
        bool pc = (lane == 0) ? false : (upc != 0);
        kv = c ? (pc ? upv : val) : kv;
        kidx = c ? (pc ? upi : midx) : kidx;
      }
    }
  }
  if (lane < K_) idxo[((size_t)b * N_ + row) * K_ + lane] = kidx;
}

// ---------- stage 2 KNN: lane = 2 rows, broadcast candidate reads, 4-way wave split ----------
__global__ __launch_bounds__(256, 1) void knn2_kernel(const float* __restrict__ x1f,
                                                      const float* __restrict__ xxf,
                                                      int* __restrict__ idxo) {
  __shared__ __align__(16) unsigned char smem[33280];
  float* tile = (float*)smem;                 // 128 cands x 64 floats = 32768 B
  float* txx  = tile + KN2_TILE * 64;         // 128 floats
  float* mD = (float*)smem;                   // merge alias: 4*64*20 floats
  unsigned short* mI = (unsigned short*)(smem + 20480);
  int bid = blockIdx.x;
  int b = bid >> 5;                            // 32 blocks per batch
  int r0 = (bid & 31) * 128;                   // 128 rows per block
  int tid = threadIdx.x;
  int lane = tid & 63, wv = tid >> 6;
  int rowA = r0 + lane, rowB = r0 + 64 + lane;
  const float* xrA = x1f + ((size_t)b * N_ + rowA) * 64;
  const float* xrB = x1f + ((size_t)b * N_ + rowB) * 64;
  float ownA[64], ownB[64];
#pragma unroll
  for (int c4 = 0; c4 < 16; ++c4) {
    float4 ta = ((const float4*)xrA)[c4];
    ownA[c4 * 4 + 0] = ta.x; ownA[c4 * 4 + 1] = ta.y;
    ownA[c4 * 4 + 2] = ta.z; ownA[c4 * 4 + 3] = ta.w;
    float4 tb = ((const float4*)xrB)[c4];
    ownB[c4 * 4 + 0] = tb.x; ownB[c4 * 4 + 1] = tb.y;
    ownB[c4 * 4 + 2] = tb.z; ownB[c4 * 4 + 3] = tb.w;
  }
  float nxxA = -xxf[(size_t)b * N_ + rowA];
  float nxxB = -xxf[(size_t)b * N_ + rowB];
  float kpA[K_], kpB[K_]; int kiA[K_], kiB[K_];
#pragma unroll
  for (int t = 0; t < K_; ++t) {
    kpA[t] = -3.0e38f; kiA[t] = 65535;
    kpB[t] = -3.0e38f; kiB[t] = 65535;
  }
  for (int t0 = 0; t0 < N_; t0 += KN2_TILE) {
    __syncthreads();
    for (int l = tid; l < KN2_TILE * 16; l += 256) {
      int ml = l >> 4, c4 = l & 15;
      ((float4*)tile)[ml * 16 + c4] =
          ((const float4*)(x1f + ((size_t)b * N_ + t0 + ml) * 64))[c4];
    }
    for (int l = tid; l < KN2_TILE; l += 256) txx[l] = xxf[(size_t)b * N_ + t0 + l];
    __syncthreads();
    for (int q = 0; q < KN2_TILE / 4; ++q) {
      int mi = wv + 4 * q;
      const float* xm = &tile[mi * 64];
      float dA = 0.f, dB = 0.f;
#pragma unroll
      for (int c4 = 0; c4 < 16; ++c4) {
        float4 a = *(const float4*)&xm[c4 * 4];   // wave-uniform addr -> broadcast
        dA = madd(ownA[c4 * 4 + 0], a.x, dA);
        dB = madd(ownB[c4 * 4 + 0], a.x, dB);
        dA = madd(ownA[c4 * 4 + 1], a.y, dA);
        dB = madd(ownB[c4 * 4 + 1], a.y, dB);
        dA = madd(ownA[c4 * 4 + 2], a.z, dA);
        dB = madd(ownB[c4 * 4 + 2], a.z, dB);
        dA = madd(ownA[c4 * 4 + 3], a.w, dA);
        dB = madd(ownB[c4 * 4 + 3], a.w, dB);
      }
      float prA = __fsub_rn(__fadd_rn(nxxA, __fadd_rn(dA, dA)), txx[mi]);
      float prB = __fsub_rn(__fadd_rn(nxxB, __fadd_rn(dB, dB)), txx[mi]);
      if (prA > kpA[K_ - 1]) ins20(kpA, kiA, prA, t0 + mi);
      if (prB > kpB[K_ - 1]) ins20(kpB, kiB, prB, t0 + mi);
    }
  }
  // ---- merge phase A (rows r0..r0+63) ----
  __syncthreads();   // tile dead; alias merge arrays
  int li = wv * 64 + lane;
#pragma unroll
  for (int t = 0; t < K_; ++t) { mD[li * K_ + t] = kpA[t]; mI[li * K_ + t] = (unsigned short)kiA[t]; }
  __syncthreads();
  if (tid < 64) {
    int h[4] = {0, 0, 0, 0};
    int* op = idxo + ((size_t)b * N_ + r0 + tid) * K_;
    for (int j = 0; j < K_; ++j) {
      float best = -3.39e38f; int bi = 0x7fffffff; int bs = 0;
#pragma unroll
      for (int s = 0; s < 4; ++s) {
        int hs = h[s];
        float dv = (hs < K_) ? mD[(s * 64 + tid) * K_ + hs] : -3.4e38f;
        int   iv = (hs < K_) ? (int)mI[(s * 64 + tid) * K_ + hs] : 0x7fffffff;
        if (dv > best || (dv == best && iv < bi)) { best = dv; bi = iv; bs = s; }
      }
      op[j] = bi;
#pragma unroll
      for (int s = 0; s < 4; ++s) h[s] += (s == bs) ? 1 : 0;
    }
  }
  // ---- merge phase B (rows r0+64..r0+127) ----
  __syncthreads();
#pragma unroll
  for (int t = 0; t < K_; ++t) { mD[li * K_ + t] = kpB[t]; mI[li * K_ + t] = (unsigned short)kiB[t]; }
  __syncthreads();
  if (tid < 64) {
    int h[4] = {0, 0, 0, 0};
    int* op = idxo + ((size_t)b * N_ + r0 + 64 + tid) * K_;
    for (int j = 0; j < K_; ++j) {
      float best = -3.39e38f; int bi = 0x7fffffff; int bs = 0;
#pragma unroll
      for (int s = 0; s < 4; ++s) {
        int hs = h[s];
        float dv = (hs < K_) ? mD[(s * 64 + tid) * K_ + hs] : -3.4e38f;
        int   iv = (hs < K_) ? (int)mI[(s * 64 + tid) * K_ + hs] : 0x7fffffff;
        if (dv > best || (dv == best && iv < bi)) { best = dv; bi = iv; bs = s; }
      }
      op[j] = bi;
#pragma unroll
      for (int s = 0; s < 4; ++s) h[s] += (s == bs) ? 1 : 0;
    }
  }
}

// ---------- exact stage-1 value path (numpy-bit-exact; feeds knn2) ----------
__device__ __forceinline__ float chain6(float w0, float w1, float w2, float w3, float w4, float w5,
                                        const float* fp) {
  float acc = __fmul_rn(w0, fp[0]);
  acc = madd(w1, fp[1], acc);
  acc = madd(w2, fp[2], acc);
  acc = madd(w3, fp[3], acc);
  acc = madd(w4, fp[4], acc);
  acc = madd(w5, fp[5], acc);
  return acc;
}

__device__ __forceinline__ float leaf_combine(const float (&r8)[8]) {
  return __fadd_rn(__fadd_rn(__fadd_rn(r8[0], r8[1]), __fadd_rn(r8[2], r8[3])),
                   __fadd_rn(__fadd_rn(r8[4], r8[5]), __fadd_rn(r8[6], r8[7])));
}

template <int VAR>
__global__ __launch_bounds__(256) void leaf1_kernel(const float* __restrict__ x,
                                                    const float* __restrict__ W1,
                                                    const int* __restrict__ idx,
                                                    const float* __restrict__ pm,
                                                    float* __restrict__ leafbuf) {
  __shared__ float feat[2560];
  __shared__ int sidx[320];
  int b = blockIdx.x >> 8;
  int bg = blockIdx.x & 255;
  int n0 = bg * 16;
  int tid = threadIdx.x;
  const float* xb = x + (size_t)b * 3 * N_;
  for (int q = tid; q < 320; q += 256) sidx[q] = idx[((size_t)b * N_ + n0) * K_ + q];
  __syncthreads();
  for (int q = tid; q < 2560; q += 256) {
    int f = q >> 3, c = q & 7;
    int n = n0 + f / 20;
    float v = 0.f;
    if (c < 3) {
      int m = sidx[f];
      v = __fsub_rn(xb[c * N_ + m], xb[c * N_ + n]);
    } else if (c < 6) {
      v = xb[(c - 3) * N_ + n];
    }
    feat[q] = v;
  }
  __syncthreads();
  int o = tid & 63, lg = tid >> 6;
  float w0 = W1[o * 6 + 0], w1 = W1[o * 6 + 1], w2 = W1[o * 6 + 2];
  float w3 = W1[o * 6 + 3], w4 = W1[o * 6 + 4], w5 = W1[o * 6 + 5];
  float mu = VAR ? pm[o] : 0.f;
  const float* fb = feat + lg * 640;
  float r8[8];
#pragma unroll
  for (int jj = 0; jj < 8; ++jj) {
    float y = chain6(w0, w1, w2, w3, w4, w5, fb + jj * 8);
    if (VAR) { float t = __fsub_rn(y, mu); y = __fmul_rn(t, t); }
    r8[jj] = y;
  }
  for (int i = 1; i < 10; ++i) {
#pragma unroll
    for (int jj = 0; jj < 8; ++jj) {
      float y = chain6(w0, w1, w2, w3, w4, w5, fb + (i * 8 + jj) * 8);
      if (VAR) { float t = __fsub_rn(y, mu); y = __fmul_rn(t, t); }
      r8[jj] = __fadd_rn(r8[jj], y);
    }
  }
  int l = bg * 4 + lg;
  leafbuf[((size_t)b * 1024 + l) * 64 + o] = leaf_combine(r8);
}

template <int MODE>
__global__ __launch_bounds__(512) void tree_kernel(const float* __restrict__ lb,
                                                   float* __restrict__ pm) {
  __shared__ float red[512];
  int t = threadIdx.x;
  int b = t >> 6, o = t & 63;
  const float* base = lb + (size_t)b * 1024 * 64 + o;
  float part[32];
#pragma unroll
  for (int p = 0; p < 32; ++p) {
    float a[32];
#pragma unroll
    for (int q = 0; q < 32; ++q) a[q] = base[(size_t)(p * 32 + q) * 64];
#pragma unroll
    for (int lev = 16; lev >= 1; lev >>= 1) {
#pragma unroll
      for (int q = 0; q < 16; ++q) {
        if (q < lev) a[q] = __fadd_rn(a[2 * q], a[2 * q + 1]);
      }
    }
    part[p] = a[0];
  }
#pragma unroll
  for (int lev = 16; lev >= 1; lev >>= 1) {
#pragma unroll
    for (int q = 0; q < 16; ++q) {
      if (q < lev) part[q] = __fadd_rn(part[2 * q], part[2 * q + 1]);
    }
  }
  red[t] = part[0];
  __syncthreads();
  if (t < 64) {
    float acc = red[t];
#pragma unroll
    for (int bb = 1; bb < 8; ++bb) acc = __fadd_rn(acc, red[bb * 64 + t]);
    float mv = __fdiv_rn(acc, 655360.0f);
    if (MODE == 0) pm[t] = mv;
    else pm[64 + t] = __fdiv_rn(1.0f, __fsqrt_rn(__fadd_rn(mv, 1e-5f)));
  }
}

__global__ __launch_bounds__(256) void final1_kernel(const float* __restrict__ x,
                                                     const float* __restrict__ W1,
                                                     const int* __restrict__ idx,
                                                     const float* __restrict__ pm,
                                                     const float* __restrict__ g,
                                                     const float* __restrict__ be,
                                                     float* __restrict__ x1f,
                                                     float* __restrict__ xxf) {
  __shared__ float feat[640];
  __shared__ int sidx[80];
  __shared__ float xrow[4][64];
  int b = blockIdx.x >> 10;
  int rg = blockIdx.x & 1023;
  int n0 = rg * 4;
  int tid = threadIdx.x;
  const float* xb = x + (size_t)b * 3 * N_;
  for (int q = tid; q < 80; q += 256) sidx[q] = idx[((size_t)b * N_ + n0) * K_ + q];
  __syncthreads();
  for (int q = tid; q < 640; q += 256) {
    int f = q >> 3, c = q & 7;
    int n = n0 + f / 20;
    float v = 0.f;
    if (c < 3) {
      int m = sidx[f];
      v = __fsub_rn(xb[c * N_ + m], xb[c * N_ + n]);
    } else if (c < 6) {
      v = xb[(c - 3) * N_ + n];
    }
    feat[q] = v;
  }
  __syncthreads();
  int o = tid & 63, lr = tid >> 6;
  float w0 = W1[o * 6 + 0], w1 = W1[o * 6 + 1], w2 = W1[o * 6 + 2];
  float w3 = W1[o * 6 + 3], w4 = W1[o * 6 + 4], w5 = W1[o * 6 + 5];
  float mu = pm[o], rs = pm[64 + o], gg = g[o], bb = be[o];
  float mx = 0.f;
  for (int j = 0; j < 20; ++j) {
    float y = chain6(w0, w1, w2, w3, w4, w5, feat + (lr * 20 + j) * 8);
    float tt = __fsub_rn(y, mu);
    float yn = __fmul_rn(tt, rs);
    float yg = __fmul_rn(yn, gg);
    float yb = __fadd_rn(yg, bb);
    float val = (yb >= 0.f) ? yb : __fmul_rn(0.2f, yb);
    mx = (j == 0) ? val : fmaxf(mx, val);
  }
  int n = n0 + lr;
  x1f[((size_t)b * N_ + n) * 64 + o] = mx;
  xrow[lr][o] = mx;
  __syncthreads();
  if (tid < 4) {
    float acc = __fmul_rn(xrow[tid][0], xrow[tid][0]);
#pragma unroll
    for (int oo = 1; oo < 64; ++oo) acc = __fadd_rn(acc, __fmul_rn(xrow[tid][oo], xrow[tid][oo]));
    xxf[(size_t)b * N_ + n0 + tid] = acc;
  }
}

// ---------- fast stage-2 value path (post-KNN: continuous, fast math OK) ----------
__global__ __launch_bounds__(256) void proj2f_kernel(const float* __restrict__ x1f,
                                                     const float* __restrict__ W2,
                                                     float* __restrict__ u, float* __restrict__ v) {
  __shared__ float w[64 * 128];
  int tid = threadIdx.x;
  for (int l = tid; l < 64 * 128; l += 256) w[l] = W2[l];
  __syncthreads();
  int i = blockIdx.x * 256 + tid;
  const float* xr = x1f + (size_t)i * 64;
  float4 xv[16];
#pragma unroll
  for (int c4 = 0; c4 < 16; ++c4) xv[c4] = ((const float4*)xr)[c4];
  float* up = u + (size_t)i * 64;
  float* vp = v + (size_t)i * 64;
#pragma unroll
  for (int og = 0; og < 16; ++og) {
    float ur[4], vr[4];
#pragma unroll
    for (int k = 0; k < 4; ++k) {
      int o = og * 4 + k;
      const float* wr = &w[o * 128];
      float ua = 0.f, ub = 0.f, ta = 0.f, tb = 0.f;
#pragma unroll
      for (int c4 = 0; c4 < 16; c4 += 2) {
        float4 wa0 = *(const float4*)&wr[c4 * 4];
        float4 wa1 = *(const float4*)&wr[c4 * 4 + 4];
        float4 wb0 = *(const float4*)&wr[64 + c4 * 4];
        float4 wb1 = *(const float4*)&wr[64 + c4 * 4 + 4];
        float4 x0 = xv[c4], x1q = xv[c4 + 1];
        ua = fmaf(wa0.x, x0.x, ua); ua = fmaf(wa0.y, x0.y, ua);
        ua = fmaf(wa0.z, x0.z, ua); ua = fmaf(wa0.w, x0.w, ua);
        ub = fmaf(wa1.x, x1q.x, ub); ub = fmaf(wa1.y, x1q.y, ub);
        ub = fmaf(wa1.z, x1q.z, ub); ub = fmaf(wa1.w, x1q.w, ub);
        ta = fmaf(wb0.x, x0.x, ta); ta = fmaf(wb0.y, x0.y, ta);
        ta = fmaf(wb0.z, x0.z, ta); ta = fmaf(wb0.w, x0.w, ta);
        tb = fmaf(wb1.x, x1q.x, tb); tb = fmaf(wb1.y, x1q.y, tb);
        tb = fmaf(wb1.z, x1q.z, tb); tb = fmaf(wb1.w, x1q.w, tb);
      }
      float uu = ua + ub, tt = ta + tb;
      ur[k] = uu; vr[k] = tt - uu;
    }
    ((float4*)up)[og] = make_float4(ur[0], ur[1], ur[2], ur[3]);
    ((float4*)vp)[og] = make_float4(vr[0], vr[1], vr[2], vr[3]);
  }
}

__global__ __launch_bounds__(256) void gatherf_kernel(const float* __restrict__ u,
                                                      const float* __restrict__ v,
                                                      const int* __restrict__ idx,
                                                      float* __restrict__ ymax,
                                                      float* __restrict__ ymin,
                                                      float* __restrict__ partbuf) {
  __shared__ float sred[4][128];
  int tid = threadIdx.x;
  int g = blockIdx.x * 32;
  int nl = tid >> 3, oc = tid & 7;
  int i = g + nl;
  int o0 = oc * 8;
  const float* vp = v + (size_t)i * 64 + o0;
  float vv[8];
  *(float4*)&vv[0] = *(const float4*)vp;
  *(float4*)&vv[4] = *(const float4*)(vp + 4);
  float s[8], q[8], mx[8], mn[8];
#pragma unroll
  for (int t = 0; t < 8; ++t) { s[t] = 0.f; q[t] = 0.f; mx[t] = -3.0e38f; mn[t] = 3.0e38f; }
  const int* ip = idx + (size_t)i * K_;
  int bbase = (i >> 12) << 12;
  for (int j = 0; j < K_; ++j) {
    int m = ip[j];
    const float* upp = u + ((size_t)(bbase + m)) * 64 + o0;
    float yv[8];
    *(float4*)&yv[0] = *(const float4*)upp;
    *(float4*)&yv[4] = *(const float4*)(upp + 4);
#pragma unroll
    for (int t = 0; t < 8; ++t) {
      float y = yv[t] + vv[t];
      s[t] += y; q[t] = fmaf(y, y, q[t]);
      mx[t] = fmaxf(mx[t], y); mn[t] = fminf(mn[t], y);
    }
  }
  float* mxp = ymax + (size_t)i * 64 + o0;
  float* mnp = ymin + (size_t)i * 64 + o0;
  *(float4*)mxp = make_float4(mx[0], mx[1], mx[2], mx[3]);
  *(float4*)(mxp + 4) = make_float4(mx[4], mx[5], mx[6], mx[7]);
  *(float4*)mnp = make_float4(mn[0], mn[1], mn[2], mn[3]);
  *(float4*)(mnp + 4) = make_float4(mn[4], mn[5], mn[6], mn[7]);
  int wv = tid >> 6;
#pragma unroll
  for (int t = 0; t < 8; ++t) {
    float sv = s[t], qv = q[t];
    sv += __shfl_xor(sv, 8);  qv += __shfl_xor(qv, 8);
    sv += __shfl_xor(sv, 16); qv += __shfl_xor(qv, 16);
    sv += __shfl_xor(sv, 32); qv += __shfl_xor(qv, 32);
    if ((tid & 63) < 8) { sred[wv][o0 + t] = sv; sred[wv][64 + o0 + t] = qv; }
  }
  __syncthreads();
  if (tid < 128) {
    float tot = (sred[0][tid] + sred[1][tid]) + (sred[2][tid] + sred[3][tid]);
    partbuf[(size_t)blockIdx.x * 128 + tid] = tot;
  }
}

__global__ void statred_kernel(const float* __restrict__ partbuf, double* __restrict__ stats) {
  int t = threadIdx.x;   // 128
  double acc = 0.0;
  for (int p = 0; p < 1024; ++p) acc += (double)partbuf[(size_t)p * 128 + t];
  stats[t] = acc;
}

__global__ void bnfin_kernel(const double* __restrict__ stats, const float* __restrict__ g,
                             const float* __restrict__ be, float* __restrict__ ss) {
  int o = threadIdx.x;
  if (o < 64) {
    const double cnt = (double)((size_t)B_ * N_ * K_);
    double mean = stats[o] / cnt;
    double var = stats[64 + o] / cnt - mean * mean;
    if (var < 0.0) var = 0.0;
    double sc = (double)g[o] / sqrt(var + 1e-5);
    ss[o] = (float)sc;
    ss[64 + o] = (float)((double)be[o] - mean * sc);
  }
}

__global__ __launch_bounds__(256) void final2f_kernel(const float* __restrict__ ymax,
                                                      const float* __restrict__ ymin,
                                                      const float* __restrict__ ss,
                                                      float* __restrict__ out) {
  __shared__ float ssh[128];
  __shared__ float vals[4][64];
  int tid = threadIdx.x;
  if (tid < 128) ssh[tid] = ss[tid];
  __syncthreads();
  int b = blockIdx.x >> 10;
  int l = blockIdx.x & 1023;
  int t = tid & 63, r = tid >> 6;
  size_t i = (size_t)b * N_ + l * 4 + r;
  float sc = ssh[t], sh = ssh[64 + t];
  float Y = (sc >= 0.f) ? ymax[i * 64 + t] : ymin[i * 64 + t];
  float val = fmaf(sc, Y, sh);
  val = (val >= 0.f) ? val : 0.2f * val;
  vals[r][t] = val;
  __syncthreads();
  if (tid < 64) {
    float4 o4 = make_float4(vals[0][tid], vals[1][tid], vals[2][tid], vals[3][tid]);
    *(float4*)&out[(size_t)b * 64 * N_ + (size_t)tid * N_ + l * 4] = o4;
  }
}

extern "C" void kernel_launch(void* const* d_in, const int* in_sizes, int n_in,
                              void* d_out, int out_size, void* d_ws, size_t ws_size,
                              hipStream_t stream) {
  const float* x  = (const float*)d_in[0];
  const float* W1 = (const float*)d_in[1];
  const float* g1 = (const float*)d_in[2];
  const float* b1 = (const float*)d_in[3];
  const float* W2 = (const float*)d_in[4];
  const float* g2 = (const float*)d_in[5];
  const float* b2 = (const float*)d_in[6];
  float* out = (float*)d_out;
  const size_t PN = (size_t)B_ * N_;

  int*    idx     = (int*)d_ws;
  float*  x1f     = (float*)(idx + PN * K_);
  float*  xxf     = x1f + PN * 64;
  float*  leafbuf = xxf + PN;
  float*  pm1     = leafbuf + (size_t)B_ * 1024 * 64;
  float*  uf      = pm1 + 128;
  float*  vf      = uf + PN * 64;
  float*  ymaxf   = vf + PN * 64;
  float*  yminf   = ymaxf + PN * 64;
  float*  partbuf = yminf + PN * 64;
  double* stats2  = (double*)(partbuf + 1024 * 128);
  float*  ss2     = (float*)(stats2 + 128);

  size_t need = (PN * K_ + PN * 64 * 5 + PN + (size_t)B_ * 1024 * 64 + 128 + 1024 * 128 + 128) * 4
              + 128 * 8;
  if (ws_size < need) return;

  const int knn1_grid = B_ * (N_ / 4);     // 8192 (wave-per-row)
  const int knn2_grid = B_ * (N_ / 128);   // 256 (128 rows per block)

  // ---- stage 1 (numpy-bit-exact; feeds knn2) ----
  knn1_kernel<<<knn1_grid, 256, 0, stream>>>(x, idx);
  leaf1_kernel<0><<<B_ * 256, 256, 0, stream>>>(x, W1, idx, pm1, leafbuf);
  tree_kernel<0><<<1, 512, 0, stream>>>(leafbuf, pm1);
  leaf1_kernel<1><<<B_ * 256, 256, 0, stream>>>(x, W1, idx, pm1, leafbuf);
  tree_kernel<1><<<1, 512, 0, stream>>>(leafbuf, pm1);
  final1_kernel<<<B_ * 1024, 256, 0, stream>>>(x, W1, idx, pm1, g1, b1, x1f, xxf);

  // ---- stage 2 (knn exact; value path fast/continuous) ----
  knn2_kernel<<<knn2_grid, 256, 0, stream>>>(x1f, xxf, idx);
  proj2f_kernel<<<(int)(PN / 256), 256, 0, stream>>>(x1f, W2, uf, vf);
  gatherf_kernel<<<(int)(PN / 32), 256, 0, stream>>>(uf, vf, idx, ymaxf, yminf, partbuf);
  statred_kernel<<<1, 128, 0, stream>>>(partbuf, stats2);
  bnfin_kernel<<<1, 64, 0, stream>>>(stats2, g2, b2, ss2);
  final2f_kernel<<<B_ * 1024, 256, 0, stream>>>(ymaxf, yminf, ss2, out);
}

// Round 18
// 1315.765 us; speedup vs baseline: 1.2694x; 1.2021x over previous
//
#include <hip/hip_runtime.h>
#include <cstdint>
#include <cstddef>

#define B_ 8
#define N_ 4096
#define K_ 20
#define MT1 1024
#define KN2_TILE 128

typedef float vfloat2 __attribute__((ext_vector_type(2)));

// separately-rounded multiply-add (numpy einsum-noopt style: no FMA contraction)
__device__ __forceinline__ float madd(float a, float b, float acc) {
  return __fadd_rn(acc, __fmul_rn(a, b));
}

__device__ __forceinline__ float xx3f(float a, float b, float c) {
  return __fadd_rn(__fadd_rn(__fmul_rn(a, a), __fmul_rn(b, b)), __fmul_rn(c, c));
}

// ---------- parallel predicated insert (r10-proven: stays in registers) ----------
__device__ __forceinline__ void ins20(float (&kp)[K_], int (&ki)[K_], float pr, int m) {
  bool c[K_];
#pragma unroll
  for (int t = 0; t < K_; ++t) c[t] = (pr > kp[t]);
#pragma unroll
  for (int t = K_ - 1; t >= 1; --t) {
    kp[t] = c[t] ? (c[t - 1] ? kp[t - 1] : pr) : kp[t];
    ki[t] = c[t] ? (c[t - 1] ? ki[t - 1] : m) : ki[t];
  }
  kp[0] = c[0] ? pr : kp[0];
  ki[0] = c[0] ? m  : ki[0];
}

// ---------- stage 1 KNN: wave-per-row collective top-k (lane = sorted slot) ----------
__global__ __launch_bounds__(256, 4) void knn1_kernel(const float* __restrict__ x, int* __restrict__ idxo) {
  __shared__ float4 tile[MT1];
  int bid = blockIdx.x;
  int b = bid / (N_ / 4);
  int r0 = (bid % (N_ / 4)) * 4;
  int tid = threadIdx.x;
  int wv = tid >> 6, lane = tid & 63;
  int row = r0 + wv;
  const float* xb = x + (size_t)b * 3 * N_;
  float ox = xb[row], oy = xb[N_ + row], oz = xb[2 * N_ + row];
  float nxxn = -xx3f(ox, oy, oz);
  float kv = -3.0e38f;
  int kidx = 0x7fffffff;
  for (int t0 = 0; t0 < N_; t0 += MT1) {
    __syncthreads();
    for (int l = tid; l < MT1; l += 256) {
      float4 p;
      p.x = xb[t0 + l]; p.y = xb[N_ + t0 + l]; p.z = xb[2 * N_ + t0 + l];
      p.w = xx3f(p.x, p.y, p.z);
      tile[l] = p;
    }
    __syncthreads();
    for (int s = 0; s < MT1; s += 64) {
      float4 p = tile[s + lane];
      float d = __fmul_rn(ox, p.x);
      d = madd(oy, p.y, d);
      d = madd(oz, p.z, d);
      float pr = __fsub_rn(__fadd_rn(nxxn, __fadd_rn(d, d)), p.w);
      float thr = __shfl(kv, 19);
      unsigned long long mask = __ballot(pr > thr);
      int mbase = t0 + s;
      while (mask) {
        int l = __ffsll(mask) - 1;
        mask &= mask - 1;
        float val = __shfl(pr, l);
        int midx = mbase + l;
        bool c = (val > kv);
        float upv = __shfl_up(kv, 1);
        int upi = __shfl_up(kidx, 1);
        int upc = __shfl_up((int)c, 1);
        bool pc = (lane == 0) ? false : (upc != 0);
        kv = c ? (pc ? upv : val) : kv;
        kidx = c ? (pc ? upi : midx) : kidx;
      }
    }
  }
  if (lane < K_) idxo[((size_t)b * N_ + row) * K_ + lane] = kidx;
}

// ---------- stage 2 KNN: lane=row, pair-interleaved tile + packed fp32 dots ----------
__global__ __launch_bounds__(256, 2) void knn2_kernel(const float* __restrict__ x1f,
                                                      const float* __restrict__ xxf,
                                                      int* __restrict__ idxo) {
  __shared__ __align__(16) unsigned char smem[33280];
  float* tile = (float*)smem;                 // 64 pairs x 128 floats (interleaved)
  float* txx  = tile + KN2_TILE * 64;         // 128 floats
  float* mD = (float*)smem;                   // merge alias: 4*64*20 floats
  unsigned short* mI = (unsigned short*)(smem + 20480);
  int bid = blockIdx.x;
  int b = bid >> 6;
  int r0 = (bid & 63) * 64;
  int tid = threadIdx.x;
  int lane = tid & 63, wv = tid >> 6;
  int row = r0 + lane;
  const float* xrow = x1f + ((size_t)b * N_ + row) * 64;
  vfloat2 own2[32];
#pragma unroll
  for (int c2 = 0; c2 < 32; ++c2) {
    own2[c2] = *(const vfloat2*)&xrow[2 * c2];
  }
  float nxxn = -xxf[(size_t)b * N_ + row];
  float kp[K_]; int ki[K_];
#pragma unroll
  for (int t = 0; t < K_; ++t) { kp[t] = -3.0e38f; ki[t] = 65535; }
  for (int t0 = 0; t0 < N_; t0 += KN2_TILE) {
    __syncthreads();
    // stage pair-interleaved: tile[p*128 + 2c + {0,1}] = {x1[2p][c], x1[2p+1][c]}
    for (int l = tid; l < 2048; l += 256) {
      int p = l >> 5, c2 = l & 31;
      const float* re = x1f + ((size_t)b * N_ + t0 + 2 * p) * 64 + 2 * c2;
      const float* ro = re + 64;
      float2 ev = *(const float2*)re;
      float2 ov = *(const float2*)ro;
      *(float4*)&tile[p * 128 + 4 * c2] = make_float4(ev.x, ov.x, ev.y, ov.y);
    }
    for (int l = tid; l < KN2_TILE; l += 256) txx[l] = xxf[(size_t)b * N_ + t0 + l];
    __syncthreads();
    // wave wv owns pairs p = wv + 4q (q ascending); 2 pair-chains in flight
    for (int q = 0; q < 16; q += 2) {
      int pA = wv + 4 * q;
      int pB = pA + 4;
      const float* tA = &tile[pA * 128];
      const float* tB = &tile[pB * 128];
      vfloat2 accA = {0.f, 0.f}, accB = {0.f, 0.f};
#pragma unroll
      for (int c2 = 0; c2 < 32; ++c2) {
        float4 fA = *(const float4*)&tA[4 * c2];   // {e2c,o2c,e2c1,o2c1}
        float4 fB = *(const float4*)&tB[4 * c2];
        vfloat2 ceA = {fA.x, fA.y}, coA = {fA.z, fA.w};
        vfloat2 ceB = {fB.x, fB.y}, coB = {fB.z, fB.w};
        vfloat2 prA, prB;
        // even channel: broadcast own2.lo to both halves
        asm("v_pk_mul_f32 %0, %1, %2 op_sel:[0,0] op_sel_hi:[0,1]"
            : "=v"(prA) : "v"(own2[c2]), "v"(ceA));
        asm("v_pk_mul_f32 %0, %1, %2 op_sel:[0,0] op_sel_hi:[0,1]"
            : "=v"(prB) : "v"(own2[c2]), "v"(ceB));
        asm("v_pk_add_f32 %0, %1, %2 op_sel:[0,0] op_sel_hi:[1,1]"
            : "=v"(accA) : "v"(accA), "v"(prA));
        asm("v_pk_add_f32 %0, %1, %2 op_sel:[0,0] op_sel_hi:[1,1]"
            : "=v"(accB) : "v"(accB), "v"(prB));
        // odd channel: broadcast own2.hi to both halves
        asm("v_pk_mul_f32 %0, %1, %2 op_sel:[1,0] op_sel_hi:[1,1]"
            : "=v"(prA) : "v"(own2[c2]), "v"(coA));
        asm("v_pk_mul_f32 %0, %1, %2 op_sel:[1,0] op_sel_hi:[1,1]"
            : "=v"(prB) : "v"(own2[c2]), "v"(coB));
        asm("v_pk_add_f32 %0, %1, %2 op_sel:[0,0] op_sel_hi:[1,1]"
            : "=v"(accA) : "v"(accA), "v"(prA));
        asm("v_pk_add_f32 %0, %1, %2 op_sel:[0,0] op_sel_hi:[1,1]"
            : "=v"(accB) : "v"(accB), "v"(prB));
      }
      int m0 = 2 * pA, m2 = 2 * pB;
      float pr0 = __fsub_rn(__fadd_rn(nxxn, __fadd_rn(accA.x, accA.x)), txx[m0]);
      float pr1 = __fsub_rn(__fadd_rn(nxxn, __fadd_rn(accA.y, accA.y)), txx[m0 + 1]);
      float pr2 = __fsub_rn(__fadd_rn(nxxn, __fadd_rn(accB.x, accB.x)), txx[m2]);
      float pr3 = __fsub_rn(__fadd_rn(nxxn, __fadd_rn(accB.y, accB.y)), txx[m2 + 1]);
      if (pr0 > kp[K_ - 1]) ins20(kp, ki, pr0, t0 + m0);
      if (pr1 > kp[K_ - 1]) ins20(kp, ki, pr1, t0 + m0 + 1);
      if (pr2 > kp[K_ - 1]) ins20(kp, ki, pr2, t0 + m2);
      if (pr3 > kp[K_ - 1]) ins20(kp, ki, pr3, t0 + m2 + 1);
    }
  }
  __syncthreads();   // tile dead; alias merge arrays
  int li = wv * 64 + lane;
#pragma unroll
  for (int t = 0; t < K_; ++t) { mD[li * K_ + t] = kp[t]; mI[li * K_ + t] = (unsigned short)ki[t]; }
  __syncthreads();
  if (tid < 64) {
    int h[4] = {0, 0, 0, 0};
    int* op = idxo + ((size_t)b * N_ + r0 + tid) * K_;
    for (int j = 0; j < K_; ++j) {
      float best = -3.39e38f; int bi = 0x7fffffff; int bs = 0;
#pragma unroll
      for (int s = 0; s < 4; ++s) {
        int hs = h[s];
        float dv = (hs < K_) ? mD[(s * 64 + tid) * K_ + hs] : -3.4e38f;
        int   iv = (hs < K_) ? (int)mI[(s * 64 + tid) * K_ + hs] : 0x7fffffff;
        if (dv > best || (dv == best && iv < bi)) { best = dv; bi = iv; bs = s; }
      }
      op[j] = bi;
#pragma unroll
      for (int s = 0; s < 4; ++s) h[s] += (s == bs) ? 1 : 0;
    }
  }
}

// ---------- exact stage-1 value path (numpy-bit-exact; feeds knn2) ----------
__device__ __forceinline__ float chain6(float w0, float w1, float w2, float w3, float w4, float w5,
                                        const float* fp) {
  float acc = __fmul_rn(w0, fp[0]);
  acc = madd(w1, fp[1], acc);
  acc = madd(w2, fp[2], acc);
  acc = madd(w3, fp[3], acc);
  acc = madd(w4, fp[4], acc);
  acc = madd(w5, fp[5], acc);
  return acc;
}

__device__ __forceinline__ float leaf_combine(const float (&r8)[8]) {
  return __fadd_rn(__fadd_rn(__fadd_rn(r8[0], r8[1]), __fadd_rn(r8[2], r8[3])),
                   __fadd_rn(__fadd_rn(r8[4], r8[5]), __fadd_rn(r8[6], r8[7])));
}

template <int VAR>
__global__ __launch_bounds__(256) void leaf1_kernel(const float* __restrict__ x,
                                                    const float* __restrict__ W1,
                                                    const int* __restrict__ idx,
                                                    const float* __restrict__ pm,
                                                    float* __restrict__ leafbuf) {
  __shared__ float feat[2560];
  __shared__ int sidx[320];
  int b = blockIdx.x >> 8;
  int bg = blockIdx.x & 255;
  int n0 = bg * 16;
  int tid = threadIdx.x;
  const float* xb = x + (size_t)b * 3 * N_;
  for (int q = tid; q < 320; q += 256) sidx[q] = idx[((size_t)b * N_ + n0) * K_ + q];
  __syncthreads();
  for (int q = tid; q < 2560; q += 256) {
    int f = q >> 3, c = q & 7;
    int n = n0 + f / 20;
    float v = 0.f;
    if (c < 3) {
      int m = sidx[f];
      v = __fsub_rn(xb[c * N_ + m], xb[c * N_ + n]);
    } else if (c < 6) {
      v = xb[(c - 3) * N_ + n];
    }
    feat[q] = v;
  }
  __syncthreads();
  int o = tid & 63, lg = tid >> 6;
  float w0 = W1[o * 6 + 0], w1 = W1[o * 6 + 1], w2 = W1[o * 6 + 2];
  float w3 = W1[o * 6 + 3], w4 = W1[o * 6 + 4], w5 = W1[o * 6 + 5];
  float mu = VAR ? pm[o] : 0.f;
  const float* fb = feat + lg * 640;
  float r8[8];
#pragma unroll
  for (int jj = 0; jj < 8; ++jj) {
    float y = chain6(w0, w1, w2, w3, w4, w5, fb + jj * 8);
    if (VAR) { float t = __fsub_rn(y, mu); y = __fmul_rn(t, t); }
    r8[jj] = y;
  }
  for (int i = 1; i < 10; ++i) {
#pragma unroll
    for (int jj = 0; jj < 8; ++jj) {
      float y = chain6(w0, w1, w2, w3, w4, w5, fb + (i * 8 + jj) * 8);
      if (VAR) { float t = __fsub_rn(y, mu); y = __fmul_rn(t, t); }
      r8[jj] = __fadd_rn(r8[jj], y);
    }
  }
  int l = bg * 4 + lg;
  leafbuf[((size_t)b * 1024 + l) * 64 + o] = leaf_combine(r8);
}

template <int MODE>
__global__ __launch_bounds__(512) void tree_kernel(const float* __restrict__ lb,
                                                   float* __restrict__ pm) {
  __shared__ float red[512];
  int t = threadIdx.x;
  int b = t >> 6, o = t & 63;
  const float* base = lb + (size_t)b * 1024 * 64 + o;
  float part[32];
#pragma unroll
  for (int p = 0; p < 32; ++p) {
    float a[32];
#pragma unroll
    for (int q = 0; q < 32; ++q) a[q] = base[(size_t)(p * 32 + q) * 64];
#pragma unroll
    for (int lev = 16; lev >= 1; lev >>= 1) {
#pragma unroll
      for (int q = 0; q < 16; ++q) {
        if (q < lev) a[q] = __fadd_rn(a[2 * q], a[2 * q + 1]);
      }
    }
    part[p] = a[0];
  }
#pragma unroll
  for (int lev = 16; lev >= 1; lev >>= 1) {
#pragma unroll
    for (int q = 0; q < 16; ++q) {
      if (q < lev) part[q] = __fadd_rn(part[2 * q], part[2 * q + 1]);
    }
  }
  red[t] = part[0];
  __syncthreads();
  if (t < 64) {
    float acc = red[t];
#pragma unroll
    for (int bb = 1; bb < 8; ++bb) acc = __fadd_rn(acc, red[bb * 64 + t]);
    float mv = __fdiv_rn(acc, 655360.0f);
    if (MODE == 0) pm[t] = mv;
    else pm[64 + t] = __fdiv_rn(1.0f, __fsqrt_rn(__fadd_rn(mv, 1e-5f)));
  }
}

__global__ __launch_bounds__(256) void final1_kernel(const float* __restrict__ x,
                                                     const float* __restrict__ W1,
                                                     const int* __restrict__ idx,
                                                     const float* __restrict__ pm,
                                                     const float* __restrict__ g,
                                                     const float* __restrict__ be,
                                                     float* __restrict__ x1f,
                                                     float* __restrict__ xxf) {
  __shared__ float feat[640];
  __shared__ int sidx[80];
  __shared__ float xrow[4][64];
  int b = blockIdx.x >> 10;
  int rg = blockIdx.x & 1023;
  int n0 = rg * 4;
  int tid = threadIdx.x;
  const float* xb = x + (size_t)b * 3 * N_;
  for (int q = tid; q < 80; q += 256) sidx[q] = idx[((size_t)b * N_ + n0) * K_ + q];
  __syncthreads();
  for (int q = tid; q < 640; q += 256) {
    int f = q >> 3, c = q & 7;
    int n = n0 + f / 20;
    float v = 0.f;
    if (c < 3) {
      int m = sidx[f];
      v = __fsub_rn(xb[c * N_ + m], xb[c * N_ + n]);
    } else if (c < 6) {
      v = xb[(c - 3) * N_ + n];
    }
    feat[q] = v;
  }
  __syncthreads();
  int o = tid & 63, lr = tid >> 6;
  float w0 = W1[o * 6 + 0], w1 = W1[o * 6 + 1], w2 = W1[o * 6 + 2];
  float w3 = W1[o * 6 + 3], w4 = W1[o * 6 + 4], w5 = W1[o * 6 + 5];
  float mu = pm[o], rs = pm[64 + o], gg = g[o], bb = be[o];
  float mx = 0.f;
  for (int j = 0; j < 20; ++j) {
    float y = chain6(w0, w1, w2, w3, w4, w5, feat + (lr * 20 + j) * 8);
    float tt = __fsub_rn(y, mu);
    float yn = __fmul_rn(tt, rs);
    float yg = __fmul_rn(yn, gg);
    float yb = __fadd_rn(yg, bb);
    float val = (yb >= 0.f) ? yb : __fmul_rn(0.2f, yb);
    mx = (j == 0) ? val : fmaxf(mx, val);
  }
  int n = n0 + lr;
  x1f[((size_t)b * N_ + n) * 64 + o] = mx;
  xrow[lr][o] = mx;
  __syncthreads();
  if (tid < 4) {
    float acc = __fmul_rn(xrow[tid][0], xrow[tid][0]);
#pragma unroll
    for (int oo = 1; oo < 64; ++oo) acc = __fadd_rn(acc, __fmul_rn(xrow[tid][oo], xrow[tid][oo]));
    xxf[(size_t)b * N_ + n0 + tid] = acc;
  }
}

// ---------- fast stage-2 value path (post-KNN: continuous, fast math OK) ----------
__global__ __launch_bounds__(256) void proj2f_kernel(const float* __restrict__ x1f,
                                                     const float* __restrict__ W2,
                                                     float* __restrict__ u, float* __restrict__ v) {
  __shared__ float w[64 * 128];
  int tid = threadIdx.x;
  for (int l = tid; l < 64 * 128; l += 256) w[l] = W2[l];
  __syncthreads();
  int i = blockIdx.x * 256 + tid;
  const float* xr = x1f + (size_t)i * 64;
  float4 xv[16];
#pragma unroll
  for (int c4 = 0; c4 < 16; ++c4) xv[c4] = ((const float4*)xr)[c4];
  float* up = u + (size_t)i * 64;
  float* vp = v + (size_t)i * 64;
#pragma unroll
  for (int og = 0; og < 16; ++og) {
    float ur[4], vr[4];
#pragma unroll
    for (int k = 0; k < 4; ++k) {
      int o = og * 4 + k;
      const float* wr = &w[o * 128];
      float ua = 0.f, ub = 0.f, ta = 0.f, tb = 0.f;
#pragma unroll
      for (int c4 = 0; c4 < 16; c4 += 2) {
        float4 wa0 = *(const float4*)&wr[c4 * 4];
        float4 wa1 = *(const float4*)&wr[c4 * 4 + 4];
        float4 wb0 = *(const float4*)&wr[64 + c4 * 4];
        float4 wb1 = *(const float4*)&wr[64 + c4 * 4 + 4];
        float4 x0 = xv[c4], x1q = xv[c4 + 1];
        ua = fmaf(wa0.x, x0.x, ua); ua = fmaf(wa0.y, x0.y, ua);
        ua = fmaf(wa0.z, x0.z, ua); ua = fmaf(wa0.w, x0.w, ua);
        ub = fmaf(wa1.x, x1q.x, ub); ub = fmaf(wa1.y, x1q.y, ub);
        ub = fmaf(wa1.z, x1q.z, ub); ub = fmaf(wa1.w, x1q.w, ub);
        ta = fmaf(wb0.x, x0.x, ta); ta = fmaf(wb0.y, x0.y, ta);
        ta = fmaf(wb0.z, x0.z, ta); ta = fmaf(wb0.w, x0.w, ta);
        tb = fmaf(wb1.x, x1q.x, tb); tb = fmaf(wb1.y, x1q.y, tb);
        tb = fmaf(wb1.z, x1q.z, tb); tb = fmaf(wb1.w, x1q.w, tb);
      }
      float uu = ua + ub, tt = ta + tb;
      ur[k] = uu; vr[k] = tt - uu;
    }
    ((float4*)up)[og] = make_float4(ur[0], ur[1], ur[2], ur[3]);
    ((float4*)vp)[og] = make_float4(vr[0], vr[1], vr[2], vr[3]);
  }
}

__global__ __launch_bounds__(256) void gatherf_kernel(const float* __restrict__ u,
                                                      const float* __restrict__ v,
                                                      const int* __restrict__ idx,
                                                      float* __restrict__ ymax,
                                                      float* __restrict__ ymin,
                                                      float* __restrict__ partbuf) {
  __shared__ float sred[4][128];
  int tid = threadIdx.x;
  int g = blockIdx.x * 32;
  int nl = tid >> 3, oc = tid & 7;
  int i = g + nl;
  int o0 = oc * 8;
  const float* vp = v + (size_t)i * 64 + o0;
  float vv[8];
  *(float4*)&vv[0] = *(const float4*)vp;
  *(float4*)&vv[4] = *(const float4*)(vp + 4);
  float s[8], q[8], mx[8], mn[8];
#pragma unroll
  for (int t = 0; t < 8; ++t) { s[t] = 0.f; q[t] = 0.f; mx[t] = -3.0e38f; mn[t] = 3.0e38f; }
  const int* ip = idx + (size_t)i * K_;
  int bbase = (i >> 12) << 12;
  for (int j = 0; j < K_; ++j) {
    int m = ip[j];
    const float* upp = u + ((size_t)(bbase + m)) * 64 + o0;
    float yv[8];
    *(float4*)&yv[0] = *(const float4*)upp;
    *(float4*)&yv[4] = *(const float4*)(upp + 4);
#pragma unroll
    for (int t = 0; t < 8; ++t) {
      float y = yv[t] + vv[t];
      s[t] += y; q[t] = fmaf(y, y, q[t]);
      mx[t] = fmaxf(mx[t], y); mn[t] = fminf(mn[t], y);
    }
  }
  float* mxp = ymax + (size_t)i * 64 + o0;
  float* mnp = ymin + (size_t)i * 64 + o0;
  *(float4*)mxp = make_float4(mx[0], mx[1], mx[2], mx[3]);
  *(float4*)(mxp + 4) = make_float4(mx[4], mx[5], mx[6], mx[7]);
  *(float4*)mnp = make_float4(mn[0], mn[1], mn[2], mn[3]);
  *(float4*)(mnp + 4) = make_float4(mn[4], mn[5], mn[6], mn[7]);
  int wv = tid >> 6;
#pragma unroll
  for (int t = 0; t < 8; ++t) {
    float sv = s[t], qv = q[t];
    sv += __shfl_xor(sv, 8);  qv += __shfl_xor(qv, 8);
    sv += __shfl_xor(sv, 16); qv += __shfl_xor(qv, 16);
    sv += __shfl_xor(sv, 32); qv += __shfl_xor(qv, 32);
    if ((tid & 63) < 8) { sred[wv][o0 + t] = sv; sred[wv][64 + o0 + t] = qv; }
  }
  __syncthreads();
  if (tid < 128) {
    float tot = (sred[0][tid] + sred[1][tid]) + (sred[2][tid] + sred[3][tid]);
    partbuf[(size_t)blockIdx.x * 128 + tid] = tot;
  }
}

__global__ void statred_kernel(const float* __restrict__ partbuf, double* __restrict__ stats) {
  int t = threadIdx.x;   // 128
  double acc = 0.0;
  for (int p = 0; p < 1024; ++p) acc += (double)partbuf[(size_t)p * 128 + t];
  stats[t] = acc;
}

__global__ void bnfin_kernel(const double* __restrict__ stats, const float* __restrict__ g,
                             const float* __restrict__ be, float* __restrict__ ss) {
  int o = threadIdx.x;
  if (o < 64) {
    const double cnt = (double)((size_t)B_ * N_ * K_);
    double mean = stats[o] / cnt;
    double var = stats[64 + o] / cnt - mean * mean;
    if (var < 0.0) var = 0.0;
    double sc = (double)g[o] / sqrt(var + 1e-5);
    ss[o] = (float)sc;
    ss[64 + o] = (float)((double)be[o] - mean * sc);
  }
}

__global__ __launch_bounds__(256) void final2f_kernel(const float* __restrict__ ymax,
                                                      const float* __restrict__ ymin,
                                                      const float* __restrict__ ss,
                                                      float* __restrict__ out) {
  __shared__ float ssh[128];
  __shared__ float vals[4][64];
  int tid = threadIdx.x;
  if (tid < 128) ssh[tid] = ss[tid];
  __syncthreads();
  int b = blockIdx.x >> 10;
  int l = blockIdx.x & 1023;
  int t = tid & 63, r = tid >> 6;
  size_t i = (size_t)b * N_ + l * 4 + r;
  float sc = ssh[t], sh = ssh[64 + t];
  float Y = (sc >= 0.f) ? ymax[i * 64 + t] : ymin[i * 64 + t];
  float val = fmaf(sc, Y, sh);
  val = (val >= 0.f) ? val : 0.2f * val;
  vals[r][t] = val;
  __syncthreads();
  if (tid < 64) {
    float4 o4 = make_float4(vals[0][tid], vals[1][tid], vals[2][tid], vals[3][tid]);
    *(float4*)&out[(size_t)b * 64 * N_ + (size_t)tid * N_ + l * 4] = o4;
  }
}

extern "C" void kernel_launch(void* const* d_in, const int* in_sizes, int n_in,
                              void* d_out, int out_size, void* d_ws, size_t ws_size,
                              hipStream_t stream) {
  const float* x  = (const float*)d_in[0];
  const float* W1 = (const float*)d_in[1];
  const float* g1 = (const float*)d_in[2];
  const float* b1 = (const float*)d_in[3];
  const float* W2 = (const float*)d_in[4];
  const float* g2 = (const float*)d_in[5];
  const float* b2 = (const float*)d_in[6];
  float* out = (float*)d_out;
  const size_t PN = (size_t)B_ * N_;

  int*    idx     = (int*)d_ws;
  float*  x1f     = (float*)(idx + PN * K_);
  float*  xxf     = x1f + PN * 64;
  float*  leafbuf = xxf + PN;
  float*  pm1     = leafbuf + (size_t)B_ * 1024 * 64;
  float*  uf      = pm1 + 128;
  float*  vf      = uf + PN * 64;
  float*  ymaxf   = vf + PN * 64;
  float*  yminf   = ymaxf + PN * 64;
  float*  partbuf = yminf + PN * 64;
  double* stats2  = (double*)(partbuf + 1024 * 128);
  float*  ss2     = (float*)(stats2 + 128);

  size_t need = (PN * K_ + PN * 64 * 5 + PN + (size_t)B_ * 1024 * 64 + 128 + 1024 * 128 + 128) * 4
              + 128 * 8;
  if (ws_size < need) return;

  const int knn1_grid = B_ * (N_ / 4);     // 8192 (wave-per-row)
  const int knn2_grid = B_ * (N_ / 64);    // 512 (64 rows per block)

  // ---- stage 1 (numpy-bit-exact; feeds knn2) ----
  knn1_kernel<<<knn1_grid, 256, 0, stream>>>(x, idx);
  leaf1_kernel<0><<<B_ * 256, 256, 0, stream>>>(x, W1, idx, pm1, leafbuf);
  tree_kernel<0><<<1, 512, 0, stream>>>(leafbuf, pm1);
  leaf1_kernel<1><<<B_ * 256, 256, 0, stream>>>(x, W1, idx, pm1, leafbuf);
  tree_kernel<1><<<1, 512, 0, stream>>>(leafbuf, pm1);
  final1_kernel<<<B_ * 1024, 256, 0, stream>>>(x, W1, idx, pm1, g1, b1, x1f, xxf);

  // ---- stage 2 (knn exact; value path fast/continuous) ----
  knn2_kernel<<<knn2_grid, 256, 0, stream>>>(x1f, xxf, idx);
  proj2f_kernel<<<(int)(PN / 256), 256, 0, stream>>>(x1f, W2, uf, vf);
  gatherf_kernel<<<(int)(PN / 32), 256, 0, stream>>>(uf, vf, idx, ymaxf, yminf, partbuf);
  statred_kernel<<<1, 128, 0, stream>>>(partbuf, stats2);
  bnfin_kernel<<<1, 64, 0, stream>>>(stats2, g2, b2, ss2);
  final2f_kernel<<<B_ * 1024, 256, 0, stream>>>(ymaxf, yminf, ss2, out);
}

// Round 19
// 1182.613 us; speedup vs baseline: 1.4123x; 1.1126x over previous
//
#include <hip/hip_runtime.h>
#include <cstdint>
#include <cstddef>

#define B_ 8
#define N_ 4096
#define K_ 20
#define MT1 1024
#define KN2_ROWS 64
#define KN2_TILE 128

// separately-rounded multiply-add (numpy einsum-noopt style: no FMA contraction)
__device__ __forceinline__ float madd(float a, float b, float acc) {
  return __fadd_rn(acc, __fmul_rn(a, b));
}

__device__ __forceinline__ float xx3f(float a, float b, float c) {
  return __fadd_rn(__fadd_rn(__fmul_rn(a, a), __fmul_rn(b, b)), __fmul_rn(c, c));
}

// ---------- parallel predicated insert (r10-proven: stays in registers) ----------
// pre: list sorted desc; equal keys keep arrival (index-asc) order. No-op if pr <= kp[19].
__device__ __forceinline__ void ins20(float (&kp)[K_], int (&ki)[K_], float pr, int m) {
  bool c[K_];
#pragma unroll
  for (int t = 0; t < K_; ++t) c[t] = (pr > kp[t]);
#pragma unroll
  for (int t = K_ - 1; t >= 1; --t) {
    kp[t] = c[t] ? (c[t - 1] ? kp[t - 1] : pr) : kp[t];
    ki[t] = c[t] ? (c[t - 1] ? ki[t - 1] : m) : ki[t];
  }
  kp[0] = c[0] ? pr : kp[0];
  ki[0] = c[0] ? m  : ki[0];
}

// ---------- stage 1 KNN: wave-per-row collective top-k (lane = sorted slot) ----------
__global__ __launch_bounds__(256, 4) void knn1_kernel(const float* __restrict__ x, int* __restrict__ idxo) {
  __shared__ float4 tile[MT1];    // 16 KiB: 1024 cands (x,y,z,xx)
  int bid = blockIdx.x;
  int b = bid / (N_ / 4);
  int r0 = (bid % (N_ / 4)) * 4;
  int tid = threadIdx.x;
  int wv = tid >> 6, lane = tid & 63;
  int row = r0 + wv;
  const float* xb = x + (size_t)b * 3 * N_;
  float ox = xb[row], oy = xb[N_ + row], oz = xb[2 * N_ + row];
  float nxxn = -xx3f(ox, oy, oz);
  float kv = -3.0e38f;
  int kidx = 0x7fffffff;
  for (int t0 = 0; t0 < N_; t0 += MT1) {
    __syncthreads();
    for (int l = tid; l < MT1; l += 256) {
      float4 p;
      p.x = xb[t0 + l]; p.y = xb[N_ + t0 + l]; p.z = xb[2 * N_ + t0 + l];
      p.w = xx3f(p.x, p.y, p.z);
      tile[l] = p;
    }
    __syncthreads();
    for (int s = 0; s < MT1; s += 64) {
      float4 p = tile[s + lane];
      float d = __fmul_rn(ox, p.x);
      d = madd(oy, p.y, d);
      d = madd(oz, p.z, d);
      float pr = __fsub_rn(__fadd_rn(nxxn, __fadd_rn(d, d)), p.w);
      float thr = __shfl(kv, 19);
      unsigned long long mask = __ballot(pr > thr);
      int mbase = t0 + s;
      while (mask) {
        int l = __ffsll(mask) - 1;
        mask &= mask - 1;
        float val = __shfl(pr, l);
        int midx = mbase + l;
        bool c = (val > kv);
        float upv = __shfl_up(kv, 1);
        int upi = __shfl_up(kidx, 1);
        int upc = __shfl_up((int)c, 1);
        bool pc = (lane == 0) ? false : (upc != 0);
        kv = c ? (pc ? upv : val) : kv;
        kidx = c ? (pc ? upi : midx) : kidx;
      }
    }
  }
  if (lane < K_) idxo[((size_t)b * N_ + row) * K_ + lane] = kidx;
}

// ---------- stage 2 KNN: lane=row, broadcast candidate reads, 4-way wave split (r12) ----------
__global__ __launch_bounds__(256, 2) void knn2_kernel(const float* __restrict__ x1f,
                                                      const float* __restrict__ xxf,
                                                      int* __restrict__ idxo) {
  __shared__ __align__(16) unsigned char smem[33280];
  float* tile = (float*)smem;                 // 128 cands x 64 floats = 32768 B
  float* txx  = tile + KN2_TILE * 64;         // 128 floats
  float* mD = (float*)smem;                   // merge alias: 4*64*20 floats
  unsigned short* mI = (unsigned short*)(smem + 20480);
  int bid = blockIdx.x;
  int b = bid >> 6;
  int r0 = (bid & 63) * KN2_ROWS;
  int tid = threadIdx.x;
  int lane = tid & 63, wv = tid >> 6;
  int row = r0 + lane;
  const float* xrow = x1f + ((size_t)b * N_ + row) * 64;
  float own[64];
#pragma unroll
  for (int c4 = 0; c4 < 16; ++c4) {
    float4 t = ((const float4*)xrow)[c4];
    own[c4 * 4 + 0] = t.x; own[c4 * 4 + 1] = t.y;
    own[c4 * 4 + 2] = t.z; own[c4 * 4 + 3] = t.w;
  }
  float nxxn = -xxf[(size_t)b * N_ + row];
  float kp[K_]; int ki[K_];
#pragma unroll
  for (int t = 0; t < K_; ++t) { kp[t] = -3.0e38f; ki[t] = 65535; }
  for (int t0 = 0; t0 < N_; t0 += KN2_TILE) {
    __syncthreads();
    for (int l = tid; l < KN2_TILE * 16; l += 256) {
      int ml = l >> 4, c4 = l & 15;
      ((float4*)tile)[ml * 16 + c4] =
          ((const float4*)(x1f + ((size_t)b * N_ + t0 + ml) * 64))[c4];
    }
    for (int l = tid; l < KN2_TILE; l += 256) txx[l] = xxf[(size_t)b * N_ + t0 + l];
    __syncthreads();
    for (int q = 0; q < KN2_TILE / 4; q += 2) {
      int mi0 = wv + 4 * q;
      int mi1 = mi0 + 4;
      const float* xm0 = &tile[mi0 * 64];
      const float* xm1 = &tile[mi1 * 64];
      float d0 = 0.f, d1 = 0.f;
#pragma unroll
      for (int c4 = 0; c4 < 16; ++c4) {
        float4 a = *(const float4*)&xm0[c4 * 4];   // wave-uniform addr -> broadcast
        float4 bq = *(const float4*)&xm1[c4 * 4];
        d0 = madd(own[c4 * 4 + 0], a.x, d0);
        d1 = madd(own[c4 * 4 + 0], bq.x, d1);
        d0 = madd(own[c4 * 4 + 1], a.y, d0);
        d1 = madd(own[c4 * 4 + 1], bq.y, d1);
        d0 = madd(own[c4 * 4 + 2], a.z, d0);
        d1 = madd(own[c4 * 4 + 2], bq.z, d1);
        d0 = madd(own[c4 * 4 + 3], a.w, d0);
        d1 = madd(own[c4 * 4 + 3], bq.w, d1);
      }
      float pr0 = __fsub_rn(__fadd_rn(nxxn, __fadd_rn(d0, d0)), txx[mi0]);
      float pr1 = __fsub_rn(__fadd_rn(nxxn, __fadd_rn(d1, d1)), txx[mi1]);
      if (pr0 > kp[K_ - 1]) ins20(kp, ki, pr0, t0 + mi0);
      if (pr1 > kp[K_ - 1]) ins20(kp, ki, pr1, t0 + mi1);
    }
  }
  __syncthreads();   // tile dead; alias merge arrays
  int li = wv * 64 + lane;
#pragma unroll
  for (int t = 0; t < K_; ++t) { mD[li * K_ + t] = kp[t]; mI[li * K_ + t] = (unsigned short)ki[t]; }
  __syncthreads();
  if (tid < 64) {
    int h[4] = {0, 0, 0, 0};
    int* op = idxo + ((size_t)b * N_ + r0 + tid) * K_;
    for (int j = 0; j < K_; ++j) {
      float best = -3.39e38f; int bi = 0x7fffffff; int bs = 0;
#pragma unroll
      for (int s = 0; s < 4; ++s) {
        int hs = h[s];
        float dv = (hs < K_) ? mD[(s * 64 + tid) * K_ + hs] : -3.4e38f;
        int   iv = (hs < K_) ? (int)mI[(s * 64 + tid) * K_ + hs] : 0x7fffffff;
        if (dv > best || (dv == best && iv < bi)) { best = dv; bi = iv; bs = s; }
      }
      op[j] = bi;
#pragma unroll
      for (int s = 0; s < 4; ++s) h[s] += (s == bs) ? 1 : 0;
    }
  }
}

// ---------- exact stage-1 value path (numpy-bit-exact; feeds knn2) ----------
__device__ __forceinline__ float chain6(float w0, float w1, float w2, float w3, float w4, float w5,
                                        const float* fp) {
  float acc = __fmul_rn(w0, fp[0]);
  acc = madd(w1, fp[1], acc);
  acc = madd(w2, fp[2], acc);
  acc = madd(w3, fp[3], acc);
  acc = madd(w4, fp[4], acc);
  acc = madd(w5, fp[5], acc);
  return acc;
}

__device__ __forceinline__ float leaf_combine(const float (&r8)[8]) {
  return __fadd_rn(__fadd_rn(__fadd_rn(r8[0], r8[1]), __fadd_rn(r8[2], r8[3])),
                   __fadd_rn(__fadd_rn(r8[4], r8[5]), __fadd_rn(r8[6], r8[7])));
}

template <int VAR>
__global__ __launch_bounds__(256) void leaf1_kernel(const float* __restrict__ x,
                                                    const float* __restrict__ W1,
                                                    const int* __restrict__ idx,
                                                    const float* __restrict__ pm,
                                                    float* __restrict__ leafbuf) {
  __shared__ float feat[2560];
  __shared__ int sidx[320];
  int b = blockIdx.x >> 8;
  int bg = blockIdx.x & 255;
  int n0 = bg * 16;
  int tid = threadIdx.x;
  const float* xb = x + (size_t)b * 3 * N_;
  for (int q = tid; q < 320; q += 256) sidx[q] = idx[((size_t)b * N_ + n0) * K_ + q];
  __syncthreads();
  for (int q = tid; q < 2560; q += 256) {
    int f = q >> 3, c = q & 7;
    int n = n0 + f / 20;
    float v = 0.f;
    if (c < 3) {
      int m = sidx[f];
      v = __fsub_rn(xb[c * N_ + m], xb[c * N_ + n]);
    } else if (c < 6) {
      v = xb[(c - 3) * N_ + n];
    }
    feat[q] = v;
  }
  __syncthreads();
  int o = tid & 63, lg = tid >> 6;
  float w0 = W1[o * 6 + 0], w1 = W1[o * 6 + 1], w2 = W1[o * 6 + 2];
  float w3 = W1[o * 6 + 3], w4 = W1[o * 6 + 4], w5 = W1[o * 6 + 5];
  float mu = VAR ? pm[o] : 0.f;
  const float* fb = feat + lg * 640;
  float r8[8];
#pragma unroll
  for (int jj = 0; jj < 8; ++jj) {
    float y = chain6(w0, w1, w2, w3, w4, w5, fb + jj * 8);
    if (VAR) { float t = __fsub_rn(y, mu); y = __fmul_rn(t, t); }
    r8[jj] = y;
  }
  for (int i = 1; i < 10; ++i) {
#pragma unroll
    for (int jj = 0; jj < 8; ++jj) {
      float y = chain6(w0, w1, w2, w3, w4, w5, fb + (i * 8 + jj) * 8);
      if (VAR) { float t = __fsub_rn(y, mu); y = __fmul_rn(t, t); }
      r8[jj] = __fadd_rn(r8[jj], y);
    }
  }
  int l = bg * 4 + lg;
  leafbuf[((size_t)b * 1024 + l) * 64 + o] = leaf_combine(r8);
}

template <int MODE>
__global__ __launch_bounds__(512) void tree_kernel(const float* __restrict__ lb,
                                                   float* __restrict__ pm) {
  __shared__ float red[512];
  int t = threadIdx.x;
  int b = t >> 6, o = t & 63;
  const float* base = lb + (size_t)b * 1024 * 64 + o;
  float part[32];
#pragma unroll
  for (int p = 0; p < 32; ++p) {
    float a[32];
#pragma unroll
    for (int q = 0; q < 32; ++q) a[q] = base[(size_t)(p * 32 + q) * 64];
#pragma unroll
    for (int lev = 16; lev >= 1; lev >>= 1) {
#pragma unroll
      for (int q = 0; q < 16; ++q) {
        if (q < lev) a[q] = __fadd_rn(a[2 * q], a[2 * q + 1]);
      }
    }
    part[p] = a[0];
  }
#pragma unroll
  for (int lev = 16; lev >= 1; lev >>= 1) {
#pragma unroll
    for (int q = 0; q < 16; ++q) {
      if (q < lev) part[q] = __fadd_rn(part[2 * q], part[2 * q + 1]);
    }
  }
  red[t] = part[0];
  __syncthreads();
  if (t < 64) {
    float acc = red[t];
#pragma unroll
    for (int bb = 1; bb < 8; ++bb) acc = __fadd_rn(acc, red[bb * 64 + t]);
    float mv = __fdiv_rn(acc, 655360.0f);
    if (MODE == 0) pm[t] = mv;
    else pm[64 + t] = __fdiv_rn(1.0f, __fsqrt_rn(__fadd_rn(mv, 1e-5f)));
  }
}

__global__ __launch_bounds__(256) void final1_kernel(const float* __restrict__ x,
                                                     const float* __restrict__ W1,
                                                     const int* __restrict__ idx,
                                                     const float* __restrict__ pm,
                                                     const float* __restrict__ g,
                                                     const float* __restrict__ be,
                                                     float* __restrict__ x1f,
                                                     float* __restrict__ xxf) {
  __shared__ float feat[640];
  __shared__ int sidx[80];
  __shared__ float xrow[4][64];
  int b = blockIdx.x >> 10;
  int rg = blockIdx.x & 1023;
  int n0 = rg * 4;
  int tid = threadIdx.x;
  const float* xb = x + (size_t)b * 3 * N_;
  for (int q = tid; q < 80; q += 256) sidx[q] = idx[((size_t)b * N_ + n0) * K_ + q];
  __syncthreads();
  for (int q = tid; q < 640; q += 256) {
    int f = q >> 3, c = q & 7;
    int n = n0 + f / 20;
    float v = 0.f;
    if (c < 3) {
      int m = sidx[f];
      v = __fsub_rn(xb[c * N_ + m], xb[c * N_ + n]);
    } else if (c < 6) {
      v = xb[(c - 3) * N_ + n];
    }
    feat[q] = v;
  }
  __syncthreads();
  int o = tid & 63, lr = tid >> 6;
  float w0 = W1[o * 6 + 0], w1 = W1[o * 6 + 1], w2 = W1[o * 6 + 2];
  float w3 = W1[o * 6 + 3], w4 = W1[o * 6 + 4], w5 = W1[o * 6 + 5];
  float mu = pm[o], rs = pm[64 + o], gg = g[o], bb = be[o];
  float mx = 0.f;
  for (int j = 0; j < 20; ++j) {
    float y = chain6(w0, w1, w2, w3, w4, w5, feat + (lr * 20 + j) * 8);
    float tt = __fsub_rn(y, mu);
    float yn = __fmul_rn(tt, rs);
    float yg = __fmul_rn(yn, gg);
    float yb = __fadd_rn(yg, bb);
    float val = (yb >= 0.f) ? yb : __fmul_rn(0.2f, yb);
    mx = (j == 0) ? val : fmaxf(mx, val);
  }
  int n = n0 + lr;
  x1f[((size_t)b * N_ + n) * 64 + o] = mx;
  xrow[lr][o] = mx;
  __syncthreads();
  if (tid < 4) {
    float acc = __fmul_rn(xrow[tid][0], xrow[tid][0]);
#pragma unroll
    for (int oo = 1; oo < 64; ++oo) acc = __fadd_rn(acc, __fmul_rn(xrow[tid][oo], xrow[tid][oo]));
    xxf[(size_t)b * N_ + n0 + tid] = acc;
  }
}

// ---------- fast stage-2 value path (post-KNN: continuous, fast math OK) ----------
__global__ __launch_bounds__(256) void proj2f_kernel(const float* __restrict__ x1f,
                                                     const float* __restrict__ W2,
                                                     float* __restrict__ u, float* __restrict__ v) {
  __shared__ float w[64 * 128];
  int tid = threadIdx.x;
  for (int l = tid; l < 64 * 128; l += 256) w[l] = W2[l];
  __syncthreads();
  int i = blockIdx.x * 256 + tid;
  const float* xr = x1f + (size_t)i * 64;
  float4 xv[16];
#pragma unroll
  for (int c4 = 0; c4 < 16; ++c4) xv[c4] = ((const float4*)xr)[c4];
  float* up = u + (size_t)i * 64;
  float* vp = v + (size_t)i * 64;
#pragma unroll
  for (int og = 0; og < 16; ++og) {
    float ur[4], vr[4];
#pragma unroll
    for (int k = 0; k < 4; ++k) {
      int o = og * 4 + k;
      const float* wr = &w[o * 128];
      float ua = 0.f, ub = 0.f, ta = 0.f, tb = 0.f;
#pragma unroll
      for (int c4 = 0; c4 < 16; c4 += 2) {
        float4 wa0 = *(const float4*)&wr[c4 * 4];
        float4 wa1 = *(const float4*)&wr[c4 * 4 + 4];
        float4 wb0 = *(const float4*)&wr[64 + c4 * 4];
        float4 wb1 = *(const float4*)&wr[64 + c4 * 4 + 4];
        float4 x0 = xv[c4], x1q = xv[c4 + 1];
        ua = fmaf(wa0.x, x0.x, ua); ua = fmaf(wa0.y, x0.y, ua);
        ua = fmaf(wa0.z, x0.z, ua); ua = fmaf(wa0.w, x0.w, ua);
        ub = fmaf(wa1.x, x1q.x, ub); ub = fmaf(wa1.y, x1q.y, ub);
        ub = fmaf(wa1.z, x1q.z, ub); ub = fmaf(wa1.w, x1q.w, ub);
        ta = fmaf(wb0.x, x0.x, ta); ta = fmaf(wb0.y, x0.y, ta);
        ta = fmaf(wb0.z, x0.z, ta); ta = fmaf(wb0.w, x0.w, ta);
        tb = fmaf(wb1.x, x1q.x, tb); tb = fmaf(wb1.y, x1q.y, tb);
        tb = fmaf(wb1.z, x1q.z, tb); tb = fmaf(wb1.w, x1q.w, tb);
      }
      float uu = ua + ub, tt = ta + tb;
      ur[k] = uu; vr[k] = tt - uu;
    }
    ((float4*)up)[og] = make_float4(ur[0], ur[1], ur[2], ur[3]);
    ((float4*)vp)[og] = make_float4(vr[0], vr[1], vr[2], vr[3]);
  }
}

__global__ __launch_bounds__(256) void gatherf_kernel(const float* __restrict__ u,
                                                      const float* __restrict__ v,
                                                      const int* __restrict__ idx,
                                                      float* __restrict__ ymax,
                                                      float* __restrict__ ymin,
                                                      float* __restrict__ partbuf) {
  __shared__ float sred[4][128];
  int tid = threadIdx.x;
  int g = blockIdx.x * 32;
  int nl = tid >> 3, oc = tid & 7;
  int i = g + nl;
  int o0 = oc * 8;
  const float* vp = v + (size_t)i * 64 + o0;
  float vv[8];
  *(float4*)&vv[0] = *(const float4*)vp;
  *(float4*)&vv[4] = *(const float4*)(vp + 4);
  float s[8], q[8], mx[8], mn[8];
#pragma unroll
  for (int t = 0; t < 8; ++t) { s[t] = 0.f; q[t] = 0.f; mx[t] = -3.0e38f; mn[t] = 3.0e38f; }
  const int* ip = idx + (size_t)i * K_;
  int bbase = (i >> 12) << 12;
  for (int j = 0; j < K_; ++j) {
    int m = ip[j];
    const float* upp = u + ((size_t)(bbase + m)) * 64 + o0;
    float yv[8];
    *(float4*)&yv[0] = *(const float4*)upp;
    *(float4*)&yv[4] = *(const float4*)(upp + 4);
#pragma unroll
    for (int t = 0; t < 8; ++t) {
      float y = yv[t] + vv[t];
      s[t] += y; q[t] = fmaf(y, y, q[t]);
      mx[t] = fmaxf(mx[t], y); mn[t] = fminf(mn[t], y);
    }
  }
  float* mxp = ymax + (size_t)i * 64 + o0;
  float* mnp = ymin + (size_t)i * 64 + o0;
  *(float4*)mxp = make_float4(mx[0], mx[1], mx[2], mx[3]);
  *(float4*)(mxp + 4) = make_float4(mx[4], mx[5], mx[6], mx[7]);
  *(float4*)mnp = make_float4(mn[0], mn[1], mn[2], mn[3]);
  *(float4*)(mnp + 4) = make_float4(mn[4], mn[5], mn[6], mn[7]);
  int wv = tid >> 6;
#pragma unroll
  for (int t = 0; t < 8; ++t) {
    float sv = s[t], qv = q[t];
    sv += __shfl_xor(sv, 8);  qv += __shfl_xor(qv, 8);
    sv += __shfl_xor(sv, 16); qv += __shfl_xor(qv, 16);
    sv += __shfl_xor(sv, 32); qv += __shfl_xor(qv, 32);
    if ((tid & 63) < 8) { sred[wv][o0 + t] = sv; sred[wv][64 + o0 + t] = qv; }
  }
  __syncthreads();
  if (tid < 128) {
    float tot = (sred[0][tid] + sred[1][tid]) + (sred[2][tid] + sred[3][tid]);
    partbuf[(size_t)blockIdx.x * 128 + tid] = tot;
  }
}

__global__ void statred_kernel(const float* __restrict__ partbuf, double* __restrict__ stats) {
  int t = threadIdx.x;   // 128
  double acc = 0.0;
  for (int p = 0; p < 1024; ++p) acc += (double)partbuf[(size_t)p * 128 + t];
  stats[t] = acc;
}

__global__ void bnfin_kernel(const double* __restrict__ stats, const float* __restrict__ g,
                             const float* __restrict__ be, float* __restrict__ ss) {
  int o = threadIdx.x;
  if (o < 64) {
    const double cnt = (double)((size_t)B_ * N_ * K_);
    double mean = stats[o] / cnt;
    double var = stats[64 + o] / cnt - mean * mean;
    if (var < 0.0) var = 0.0;
    double sc = (double)g[o] / sqrt(var + 1e-5);
    ss[o] = (float)sc;
    ss[64 + o] = (float)((double)be[o] - mean * sc);
  }
}

__global__ __launch_bounds__(256) void final2f_kernel(const float* __restrict__ ymax,
                                                      const float* __restrict__ ymin,
                                                      const float* __restrict__ ss,
                                                      float* __restrict__ out) {
  __shared__ float ssh[128];
  __shared__ float vals[4][64];
  int tid = threadIdx.x;
  if (tid < 128) ssh[tid] = ss[tid];
  __syncthreads();
  int b = blockIdx.x >> 10;
  int l = blockIdx.x & 1023;
  int t = tid & 63, r = tid >> 6;
  size_t i = (size_t)b * N_ + l * 4 + r;
  float sc = ssh[t], sh = ssh[64 + t];
  float Y = (sc >= 0.f) ? ymax[i * 64 + t] : ymin[i * 64 + t];
  float val = fmaf(sc, Y, sh);
  val = (val >= 0.f) ? val : 0.2f * val;
  vals[r][t] = val;
  __syncthreads();
  if (tid < 64) {
    float4 o4 = make_float4(vals[0][tid], vals[1][tid], vals[2][tid], vals[3][tid]);
    *(float4*)&out[(size_t)b * 64 * N_ + (size_t)tid * N_ + l * 4] = o4;
  }
}

extern "C" void kernel_launch(void* const* d_in, const int* in_sizes, int n_in,
                              void* d_out, int out_size, void* d_ws, size_t ws_size,
                              hipStream_t stream) {
  const float* x  = (const float*)d_in[0];
  const float* W1 = (const float*)d_in[1];
  const float* g1 = (const float*)d_in[2];
  const float* b1 = (const float*)d_in[3];
  const float* W2 = (const float*)d_in[4];
  const float* g2 = (const float*)d_in[5];
  const float* b2 = (const float*)d_in[6];
  float* out = (float*)d_out;
  const size_t PN = (size_t)B_ * N_;

  int*    idx     = (int*)d_ws;
  float*  x1f     = (float*)(idx + PN * K_);
  float*  xxf     = x1f + PN * 64;
  float*  leafbuf = xxf + PN;
  float*  pm1     = leafbuf + (size_t)B_ * 1024 * 64;
  float*  uf      = pm1 + 128;
  float*  vf      = uf + PN * 64;
  float*  ymaxf   = vf + PN * 64;
  float*  yminf   = ymaxf + PN * 64;
  float*  partbuf = yminf + PN * 64;
  double* stats2  = (double*)(partbuf + 1024 * 128);
  float*  ss2     = (float*)(stats2 + 128);

  size_t need = (PN * K_ + PN * 64 * 5 + PN + (size_t)B_ * 1024 * 64 + 128 + 1024 * 128 + 128) * 4
              + 128 * 8;
  if (ws_size < need) return;

  const int knn1_grid = B_ * (N_ / 4);          // 8192 (wave-per-row)
  const int knn2_grid = B_ * (N_ / KN2_ROWS);   // 512

  // ---- stage 1 (numpy-bit-exact; feeds knn2) ----
  knn1_kernel<<<knn1_grid, 256, 0, stream>>>(x, idx);
  leaf1_kernel<0><<<B_ * 256, 256, 0, stream>>>(x, W1, idx, pm1, leafbuf);
  tree_kernel<0><<<1, 512, 0, stream>>>(leafbuf, pm1);
  leaf1_kernel<1><<<B_ * 256, 256, 0, stream>>>(x, W1, idx, pm1, leafbuf);
  tree_kernel<1><<<1, 512, 0, stream>>>(leafbuf, pm1);
  final1_kernel<<<B_ * 1024, 256, 0, stream>>>(x, W1, idx, pm1, g1, b1, x1f, xxf);

  // ---- stage 2 (knn exact; value path fast/continuous) ----
  knn2_kernel<<<knn2_grid, 256, 0, stream>>>(x1f, xxf, idx);
  proj2f_kernel<<<(int)(PN / 256), 256, 0, stream>>>(x1f, W2, uf, vf);
  gatherf_kernel<<<(int)(PN / 32), 256, 0, stream>>>(uf, vf, idx, ymaxf, yminf, partbuf);
  statred_kernel<<<1, 128, 0, stream>>>(partbuf, stats2);
  bnfin_kernel<<<1, 64, 0, stream>>>(stats2, g2, b2, ss2);
  final2f_kernel<<<B_ * 1024, 256, 0, stream>>>(ymaxf, yminf, ss2, out);
}